// Round 1
// baseline (2553.215 us; speedup 1.0000x reference)
//
#include <hip/hip_runtime.h>
#include <hip/hip_bf16.h>
#include <stdint.h>

// ---------------------------------------------------------------------------
// UVSeamGNN: 2x SAGEConv (mean agg) + edge MLP.
// Key factorization: e1-layer input [h[src], h[dst], attr] @ w_e1 ==
//   (h2 @ W_s)[src] + (h2 @ W_d)[dst] + attr @ W_a  -> per-node GEMMs.
// Workspace layout (floats):
//   cnt  [N]            @ 0
//   agg1 [N,6]          @ N
//   cat2 [N,256]        @ 7N     (cols 0..127 = h1, cols 128..255 = agg2/mean2;
//                                 later reused as Pcat: cols 0..127 = Ps, 128..255 = Pd)
//   h2   [N,128]        @ 263N
// Total 391N floats = 156.4 MB.
// ---------------------------------------------------------------------------

// ---- scatter layer 1: agg1[d] += x[s], cnt[d] += 1 ----
__global__ void scatter1_kernel(const float* __restrict__ x,
                                const int* __restrict__ ei,
                                float* __restrict__ agg1,
                                float* __restrict__ cnt, int E) {
  int e = blockIdx.x * blockDim.x + threadIdx.x;
  if (e >= E) return;
  int s = ei[e];
  int d = ei[E + e];
#pragma unroll
  for (int j = 0; j < 6; j++) atomicAdd(&agg1[d * 6 + j], x[s * 6 + j]);
  atomicAdd(&cnt[d], 1.0f);
}

// ---- dense layer 1: h1 = relu(x @ w_root + mean1 @ w_neigh + b) ----
// one block (128 threads) per node; writes into cat2 cols 0..127 (ldc=256)
__global__ void dense1_kernel(const float* __restrict__ x,
                              const float* __restrict__ agg1,
                              const float* __restrict__ cnt,
                              const float* __restrict__ w_root,
                              const float* __restrict__ w_neigh,
                              const float* __restrict__ b,
                              float* __restrict__ out, int N) {
  int n = blockIdx.x;
  int m = threadIdx.x;
  if (n >= N) return;
  float inv = 1.0f / fmaxf(cnt[n], 1.0f);
  float s = b[m];
#pragma unroll
  for (int j = 0; j < 6; j++) {
    float xv = x[n * 6 + j];
    float mv = agg1[n * 6 + j] * inv;
    s += xv * w_root[j * 128 + m] + mv * w_neigh[j * 128 + m];
  }
  out[(size_t)n * 256 + m] = fmaxf(s, 0.0f);
}

// ---- scatter layer 2: agg2[d, j] += h1[s, j]  (h1 = cat2 cols 0..127, agg2 = cols 128..255)
__global__ void scatter2_kernel(const float* __restrict__ cat2_r,
                                const int* __restrict__ ei,
                                float* __restrict__ cat2_w, int E) {
  size_t idx = (size_t)blockIdx.x * blockDim.x + threadIdx.x;
  if (idx >= (size_t)E * 128) return;
  int e = (int)(idx >> 7);
  int j = (int)(idx & 127);
  int s = ei[e];
  int d = ei[E + e];
  atomicAdd(&cat2_w[(size_t)d * 256 + 128 + j], cat2_r[(size_t)s * 256 + j]);
}

// ---- divide agg2 by count in place (cols 128..255 of cat2) ----
__global__ void finalize_mean_kernel(float* __restrict__ cat2,
                                     const float* __restrict__ cnt, int N) {
  int idx = blockIdx.x * blockDim.x + threadIdx.x;
  if (idx >= N * 128) return;
  int n = idx >> 7;
  int j = idx & 127;
  float inv = 1.0f / fmaxf(cnt[n], 1.0f);
  cat2[(size_t)n * 256 + 128 + j] *= inv;
}

// ---- tiled fp32 GEMM: C[M,128] (ldc) {=, +=} A[M,128] (lda) @ B[128,128] (+bias, relu)
// BM=64, BK=32, block=256 threads, micro-tile 4x8 per thread.
template <bool BETA, bool BIAS, bool RELU>
__global__ __launch_bounds__(256) void gemm_k128_n128(
    const float* __restrict__ A, int lda, const float* __restrict__ B,
    const float* __restrict__ bias, float* __restrict__ C, int ldc, int M) {
  __shared__ float at[32][64 + 4];    // A tile transposed [k][row]
  __shared__ float bt[32][128 + 8];   // B tile [k][col], pad keeps 16B align

  int tid = threadIdx.x;
  int m0 = blockIdx.x * 64;
  int rg = tid >> 4;       // 0..15
  int cg = tid & 15;       // 0..15
  int r0 = rg * 4;
  int c0 = cg * 8;

  float acc[4][8];
#pragma unroll
  for (int i = 0; i < 4; i++)
#pragma unroll
    for (int j = 0; j < 8; j++) acc[i][j] = 0.0f;

  for (int kk = 0; kk < 128; kk += 32) {
    __syncthreads();
    // stage A: 64 rows x 32 k, 2 float4 per thread, store transposed
#pragma unroll
    for (int i = 0; i < 2; i++) {
      int L = tid + 256 * i;     // 0..511
      int r = L >> 3;            // 0..63
      int c4 = (L & 7) * 4;      // 0..28
      float4 v = make_float4(0.f, 0.f, 0.f, 0.f);
      int row = m0 + r;
      if (row < M) v = *(const float4*)(A + (size_t)row * lda + kk + c4);
      at[c4 + 0][r] = v.x;
      at[c4 + 1][r] = v.y;
      at[c4 + 2][r] = v.z;
      at[c4 + 3][r] = v.w;
    }
    // stage B: 32 k x 128 cols, 4 float4 per thread
#pragma unroll
    for (int i = 0; i < 4; i++) {
      int L = tid + 256 * i;     // 0..1023
      int k = L >> 5;            // 0..31
      int c4 = (L & 31) * 4;     // 0..124
      float4 v = *(const float4*)(B + (size_t)(kk + k) * 128 + c4);
      *(float4*)&bt[k][c4] = v;
    }
    __syncthreads();
#pragma unroll
    for (int k = 0; k < 32; k++) {
      float a4[4], b8[8];
      *(float4*)a4 = *(const float4*)&at[k][r0];
      *(float4*)&b8[0] = *(const float4*)&bt[k][c0];
      *(float4*)&b8[4] = *(const float4*)&bt[k][c0 + 4];
#pragma unroll
      for (int i = 0; i < 4; i++)
#pragma unroll
        for (int j = 0; j < 8; j++) acc[i][j] += a4[i] * b8[j];
    }
  }
#pragma unroll
  for (int i = 0; i < 4; i++) {
    int row = m0 + r0 + i;
    if (row < M) {
      float* cp = C + (size_t)row * ldc + c0;
#pragma unroll
      for (int j = 0; j < 8; j++) {
        float v = acc[i][j];
        if (BETA) v += cp[j];
        if (BIAS) v += bias[c0 + j];
        if (RELU) v = fmaxf(v, 0.0f);
        cp[j] = v;
      }
    }
  }
}

// ---- fused edge MLP: out[e] = relu(relu(Ps[s]+Pd[d]+attr@Wa+b1) @ W2 + b2) @ W3 + b3
// one wave per edge; W2 column per lane in registers (loaded once per block).
__global__ __launch_bounds__(256) void edge_mlp_kernel(
    const float* __restrict__ Pcat, const int* __restrict__ ei,
    const float* __restrict__ attr, const float* __restrict__ w_e1,
    const float* __restrict__ b_e1, const float* __restrict__ w_e2,
    const float* __restrict__ b_e2, const float* __restrict__ w_e3,
    const float* __restrict__ b_e3, float* __restrict__ out, int E) {
  __shared__ float sWa[4 * 128];
  __shared__ float sB1[128];
  __shared__ float sV[4][128];

  int tid = threadIdx.x;
  int wave = tid >> 6;
  int lane = tid & 63;

  for (int i = tid; i < 512; i += 256) sWa[i] = w_e1[256 * 128 + i];
  if (tid < 128) sB1[tid] = b_e1[tid];

  // lane owns output column j=lane of W_e2 [128,64]
  float w2c[128];
#pragma unroll
  for (int k = 0; k < 128; k++) w2c[k] = w_e2[k * 64 + lane];
  float w3 = w_e3[lane];
  float bb2 = b_e2[lane];
  float bb3 = b_e3[0];
  __syncthreads();

  for (int base = blockIdx.x * 4; base < E; base += gridDim.x * 4) {
    int e = base + wave;
    bool act = e < E;
    if (act) {
      int s = ei[e];
      int d = ei[E + e];
      float4 a4 = *(const float4*)(attr + (size_t)e * 4);
      const float* ps = Pcat + (size_t)s * 256;
      const float* pd = Pcat + (size_t)d * 256 + 128;
#pragma unroll
      for (int h = 0; h < 2; h++) {
        int m = lane + 64 * h;
        float t = sB1[m] + a4.x * sWa[m] + a4.y * sWa[128 + m] +
                  a4.z * sWa[256 + m] + a4.w * sWa[384 + m];
        t += ps[m] + pd[m - 128 + 128];  // pd already offset by +128
        sV[wave][m] = fmaxf(t, 0.0f);
      }
    }
    __syncthreads();
    if (act) {
      float acc0 = 0.0f, acc1 = 0.0f;
#pragma unroll
      for (int k = 0; k < 128; k += 2) {
        acc0 += sV[wave][k] * w2c[k];
        acc1 += sV[wave][k + 1] * w2c[k + 1];
      }
      float u = fmaxf(acc0 + acc1 + bb2, 0.0f);
      float p = u * w3;
#pragma unroll
      for (int off = 32; off > 0; off >>= 1) p += __shfl_down(p, off, 64);
      if (lane == 0) out[e] = p + bb3;
    }
    __syncthreads();
  }
}

extern "C" void kernel_launch(void* const* d_in, const int* in_sizes, int n_in,
                              void* d_out, int out_size, void* d_ws,
                              size_t ws_size, hipStream_t stream) {
  const float* x       = (const float*)d_in[0];
  const int*   ei      = (const int*)d_in[1];
  const float* attr    = (const float*)d_in[2];
  const float* w1_root = (const float*)d_in[3];
  const float* w1_neigh= (const float*)d_in[4];
  const float* b1      = (const float*)d_in[5];
  const float* w2_root = (const float*)d_in[6];
  const float* w2_neigh= (const float*)d_in[7];
  const float* b2      = (const float*)d_in[8];
  const float* w_e1    = (const float*)d_in[9];
  const float* b_e1    = (const float*)d_in[10];
  const float* w_e2    = (const float*)d_in[11];
  const float* b_e2    = (const float*)d_in[12];
  const float* w_e3    = (const float*)d_in[13];
  const float* b_e3    = (const float*)d_in[14];
  float* out = (float*)d_out;

  int N = in_sizes[0] / 6;
  int E = in_sizes[2] / 4;

  float* ws   = (float*)d_ws;
  float* cnt  = ws;                       // [N]
  float* agg1 = ws + N;                   // [N,6]
  float* cat2 = ws + (size_t)7 * N;       // [N,256]
  float* h2   = ws + (size_t)263 * N;     // [N,128]

  // zero cnt+agg1 and the whole cat2 (agg2 region needs zeros)
  hipMemsetAsync(cnt, 0, (size_t)7 * N * sizeof(float), stream);
  hipMemsetAsync(cat2, 0, (size_t)256 * N * sizeof(float), stream);

  // layer 1
  scatter1_kernel<<<(E + 255) / 256, 256, 0, stream>>>(x, ei, agg1, cnt, E);
  dense1_kernel<<<N, 128, 0, stream>>>(x, agg1, cnt, w1_root, w1_neigh, b1,
                                       cat2, N);
  // layer 2 aggregation
  size_t total2 = (size_t)E * 128;
  scatter2_kernel<<<(unsigned)((total2 + 255) / 256), 256, 0, stream>>>(
      cat2, ei, cat2, E);
  finalize_mean_kernel<<<(N * 128 + 255) / 256, 256, 0, stream>>>(cat2, cnt, N);

  // layer 2 dense: h2 = relu(h1 @ w2_root + mean2 @ w2_neigh + b2)
  int gblocks = (N + 63) / 64;
  gemm_k128_n128<false, false, false><<<gblocks, 256, 0, stream>>>(
      cat2, 256, w2_root, nullptr, h2, 128, N);
  gemm_k128_n128<true, true, true><<<gblocks, 256, 0, stream>>>(
      cat2 + 128, 256, w2_neigh, b2, h2, 128, N);

  // node-factorized edge-layer projections: Pcat = [h2 @ W_s | h2 @ W_d]
  gemm_k128_n128<false, false, false><<<gblocks, 256, 0, stream>>>(
      h2, 128, w_e1, nullptr, cat2, 256, N);
  gemm_k128_n128<false, false, false><<<gblocks, 256, 0, stream>>>(
      h2, 128, w_e1 + 128 * 128, nullptr, cat2 + 128, 256, N);

  // fused edge MLP
  edge_mlp_kernel<<<2048, 256, 0, stream>>>(cat2, ei, attr, w_e1, b_e1, w_e2,
                                            b_e2, w_e3, b_e3, out, E);
}

// Round 2
// 1123.032 us; speedup vs baseline: 2.2735x; 2.2735x over previous
//
#include <hip/hip_runtime.h>
#include <hip/hip_bf16.h>
#include <stdint.h>

// ---------------------------------------------------------------------------
// UVSeamGNN: 2x SAGEConv (mean agg) + edge MLP.
// R2: CSR-based aggregation (no feature atomics), fused K=256 node GEMM,
//     in-place h2, edge MLP as tiled LDS GEMM (64-edge tiles, persistent).
// Workspace (4B words), N=100000, E=1600000:
//   rowptr  [N+1]   @ 0
//   cursor  [N]     @ 100004
//   partial [512]   @ 200004
//   csr2    [2E]    @ 200516   (packed: src | dst<<17 | eid<<34)
//   cat2    [N,256] @ 3400516  (cols 0..127: h1 then Ps; cols 128..255:
//                               mean2 then h2 then Pd)
//   mean1   [N,6]   @ 29000516
// total ~118.4 MB
// ---------------------------------------------------------------------------

#define NMASK 0x1FFFF

// ---- CSR build ----
__global__ void hist_kernel(const int* __restrict__ ei, int* __restrict__ cnt,
                            int E) {
  int e = blockIdx.x * blockDim.x + threadIdx.x;
  if (e < E) atomicAdd(&cnt[ei[E + e]], 1);
}

__global__ void scan_block_sums(const int* __restrict__ cnt,
                                int* __restrict__ partial, int N) {
  __shared__ int red[256];
  int t = threadIdx.x;
  int n = blockIdx.x * 256 + t;
  red[t] = (n < N) ? cnt[n] : 0;
  __syncthreads();
  for (int off = 128; off; off >>= 1) {
    if (t < off) red[t] += red[t + off];
    __syncthreads();
  }
  if (t == 0) partial[blockIdx.x] = red[0];
}

__global__ void scan_partials(int* __restrict__ partial, int* __restrict__ rowptr,
                              int NBLK, int E, int N) {
  __shared__ int sc[512];
  int t = threadIdx.x;
  int v = (t < NBLK) ? partial[t] : 0;
  sc[t] = v;
  __syncthreads();
  for (int off = 1; off < 512; off <<= 1) {
    int a = (t >= off) ? sc[t - off] : 0;
    __syncthreads();
    sc[t] += a;
    __syncthreads();
  }
  if (t < NBLK) partial[t] = sc[t] - v;  // exclusive
  if (t == 0) rowptr[N] = E;
}

__global__ void scan_final(const int* __restrict__ partial,
                           int* __restrict__ cursor, int* __restrict__ rowptr,
                           int N) {
  __shared__ int sc[256];
  int t = threadIdx.x;
  int n = blockIdx.x * 256 + t;
  int v = (n < N) ? cursor[n] : 0;
  sc[t] = v;
  __syncthreads();
  for (int off = 1; off < 256; off <<= 1) {
    int a = (t >= off) ? sc[t - off] : 0;
    __syncthreads();
    sc[t] += a;
    __syncthreads();
  }
  int excl = partial[blockIdx.x] + sc[t] - v;
  if (n < N) {
    rowptr[n] = excl;
    cursor[n] = excl;
  }
}

__global__ void scatter_csr(const int* __restrict__ ei, int* __restrict__ cursor,
                            uint2* __restrict__ csr2, int E) {
  int e = blockIdx.x * blockDim.x + threadIdx.x;
  if (e >= E) return;
  int s = ei[e];
  int d = ei[E + e];
  int pos = atomicAdd(&cursor[d], 1);
  unsigned long long v = (unsigned long long)(unsigned)s |
                         ((unsigned long long)(unsigned)d << 17) |
                         ((unsigned long long)(unsigned)e << 34);
  csr2[pos] = make_uint2((unsigned)v, (unsigned)(v >> 32));
}

// ---- layer-1 mean aggregation: mean1[n][0..5] ----
__global__ void agg1_kernel(const float* __restrict__ x,
                            const int* __restrict__ rowptr,
                            const uint2* __restrict__ csr2,
                            float* __restrict__ mean1, int N) {
  int n = blockIdx.x * blockDim.x + threadIdx.x;
  if (n >= N) return;
  int beg = rowptr[n], end = rowptr[n + 1];
  float s0 = 0, s1 = 0, s2 = 0, s3 = 0, s4 = 0, s5 = 0;
  for (int i = beg; i < end; i++) {
    int s = (int)(csr2[i].x & NMASK);
    const float2* xp = (const float2*)(x + (size_t)s * 6);
    float2 a = xp[0], b = xp[1], c = xp[2];
    s0 += a.x; s1 += a.y; s2 += b.x; s3 += b.y; s4 += c.x; s5 += c.y;
  }
  float inv = 1.0f / (float)max(end - beg, 1);
  float* mp = mean1 + (size_t)n * 6;
  mp[0] = s0 * inv; mp[1] = s1 * inv; mp[2] = s2 * inv;
  mp[3] = s3 * inv; mp[4] = s4 * inv; mp[5] = s5 * inv;
}

// ---- dense layer 1: h1 = relu(x @ w_root + mean1 @ w_neigh + b) ----
__global__ void dense1_kernel(const float* __restrict__ x,
                              const float* __restrict__ mean1,
                              const float* __restrict__ w_root,
                              const float* __restrict__ w_neigh,
                              const float* __restrict__ b,
                              float* __restrict__ out, int N) {
  int n = blockIdx.x;
  int m = threadIdx.x;
  if (n >= N) return;
  float s = b[m];
#pragma unroll
  for (int j = 0; j < 6; j++) {
    s += x[(size_t)n * 6 + j] * w_root[j * 128 + m] +
         mean1[(size_t)n * 6 + j] * w_neigh[j * 128 + m];
  }
  out[(size_t)n * 256 + m] = fmaxf(s, 0.0f);
}

// ---- layer-2 mean aggregation: cat2 cols 128..255 = mean of h1[src] rows ----
// one wave per node; reads h1 (cols 0..127), writes cols 128..255 (disjoint).
__global__ __launch_bounds__(256) void agg2_kernel(
    const float* __restrict__ cat2_r, float* __restrict__ cat2_w,
    const int* __restrict__ rowptr, const uint2* __restrict__ csr2, int N) {
  int n = blockIdx.x * 4 + (threadIdx.x >> 6);
  int lane = threadIdx.x & 63;
  if (n >= N) return;
  int beg = rowptr[n], end = rowptr[n + 1];
  float a0 = 0.0f, a1 = 0.0f;
  int i = beg;
  for (; i + 2 <= end; i += 2) {
    int s0 = (int)(csr2[i].x & NMASK);
    int s1 = (int)(csr2[i + 1].x & NMASK);
    const float* p0 = cat2_r + (size_t)s0 * 256;
    const float* p1 = cat2_r + (size_t)s1 * 256;
    float v0 = p0[lane], v1 = p0[64 + lane];
    float w0 = p1[lane], w1 = p1[64 + lane];
    a0 += v0 + w0;
    a1 += v1 + w1;
  }
  if (i < end) {
    int s = (int)(csr2[i].x & NMASK);
    const float* p = cat2_r + (size_t)s * 256;
    a0 += p[lane];
    a1 += p[64 + lane];
  }
  float inv = 1.0f / (float)max(end - beg, 1);
  cat2_w[(size_t)n * 256 + 128 + lane] = a0 * inv;
  cat2_w[(size_t)n * 256 + 192 + lane] = a1 * inv;
}

// ---- tiled fp32 GEMM: C[M,128] (ldc) = A[M,128] (lda) @ B[128,128] (+bias,relu)
template <bool BIAS, bool RELU>
__global__ __launch_bounds__(256) void gemm_k128_n128(
    const float* __restrict__ A, int lda, const float* __restrict__ B,
    const float* __restrict__ bias, float* __restrict__ C, int ldc, int M) {
  __shared__ float at[32][64 + 4];
  __shared__ float bt[32][128 + 8];

  int tid = threadIdx.x;
  int m0 = blockIdx.x * 64;
  int r0 = (tid >> 4) * 4;
  int c0 = (tid & 15) * 8;

  float acc[4][8];
#pragma unroll
  for (int i = 0; i < 4; i++)
#pragma unroll
    for (int j = 0; j < 8; j++) acc[i][j] = 0.0f;

  for (int kk = 0; kk < 128; kk += 32) {
    __syncthreads();
#pragma unroll
    for (int i = 0; i < 2; i++) {
      int L = tid + 256 * i;
      int r = L >> 3;
      int c4 = (L & 7) * 4;
      float4 v = make_float4(0.f, 0.f, 0.f, 0.f);
      int row = m0 + r;
      if (row < M) v = *(const float4*)(A + (size_t)row * lda + kk + c4);
      at[c4 + 0][r] = v.x; at[c4 + 1][r] = v.y;
      at[c4 + 2][r] = v.z; at[c4 + 3][r] = v.w;
    }
#pragma unroll
    for (int i = 0; i < 4; i++) {
      int L = tid + 256 * i;
      int k = L >> 5;
      int c4 = (L & 31) * 4;
      *(float4*)&bt[k][c4] = *(const float4*)(B + (size_t)(kk + k) * 128 + c4);
    }
    __syncthreads();
#pragma unroll
    for (int k = 0; k < 32; k++) {
      float a4[4], b8[8];
      *(float4*)a4 = *(const float4*)&at[k][r0];
      *(float4*)&b8[0] = *(const float4*)&bt[k][c0];
      *(float4*)&b8[4] = *(const float4*)&bt[k][c0 + 4];
#pragma unroll
      for (int i = 0; i < 4; i++)
#pragma unroll
        for (int j = 0; j < 8; j++) acc[i][j] += a4[i] * b8[j];
    }
  }
#pragma unroll
  for (int i = 0; i < 4; i++) {
    int row = m0 + r0 + i;
    if (row < M) {
      float* cp = C + (size_t)row * ldc + c0;
#pragma unroll
      for (int j = 0; j < 8; j++) {
        float v = acc[i][j];
        if (BIAS) v += bias[c0 + j];
        if (RELU) v = fmaxf(v, 0.0f);
        cp[j] = v;
      }
    }
  }
}

// ---- fused K=256 GEMM: C = relu(A[M,256] @ [B0;B1] + bias), in-place safe
// (each block reads only its own 64 rows, writes at the end)
__global__ __launch_bounds__(256) void gemm_k256_n128(
    const float* __restrict__ A, const float* __restrict__ B0,
    const float* __restrict__ B1, const float* __restrict__ bias,
    float* __restrict__ C, int M) {
  __shared__ float at[32][64 + 4];
  __shared__ float bt[32][128 + 8];

  int tid = threadIdx.x;
  int m0 = blockIdx.x * 64;
  int r0 = (tid >> 4) * 4;
  int c0 = (tid & 15) * 8;

  float acc[4][8];
#pragma unroll
  for (int i = 0; i < 4; i++)
#pragma unroll
    for (int j = 0; j < 8; j++) acc[i][j] = 0.0f;

  for (int kk = 0; kk < 256; kk += 32) {
    const float* Bk = (kk < 128) ? (B0 + (size_t)kk * 128)
                                 : (B1 + (size_t)(kk - 128) * 128);
    __syncthreads();
#pragma unroll
    for (int i = 0; i < 2; i++) {
      int L = tid + 256 * i;
      int r = L >> 3;
      int c4 = (L & 7) * 4;
      float4 v = make_float4(0.f, 0.f, 0.f, 0.f);
      int row = m0 + r;
      if (row < M) v = *(const float4*)(A + (size_t)row * 256 + kk + c4);
      at[c4 + 0][r] = v.x; at[c4 + 1][r] = v.y;
      at[c4 + 2][r] = v.z; at[c4 + 3][r] = v.w;
    }
#pragma unroll
    for (int i = 0; i < 4; i++) {
      int L = tid + 256 * i;
      int k = L >> 5;
      int c4 = (L & 31) * 4;
      *(float4*)&bt[k][c4] = *(const float4*)(Bk + (size_t)k * 128 + c4);
    }
    __syncthreads();
#pragma unroll
    for (int k = 0; k < 32; k++) {
      float a4[4], b8[8];
      *(float4*)a4 = *(const float4*)&at[k][r0];
      *(float4*)&b8[0] = *(const float4*)&bt[k][c0];
      *(float4*)&b8[4] = *(const float4*)&bt[k][c0 + 4];
#pragma unroll
      for (int i = 0; i < 4; i++)
#pragma unroll
        for (int j = 0; j < 8; j++) acc[i][j] += a4[i] * b8[j];
    }
  }
#pragma unroll
  for (int i = 0; i < 4; i++) {
    int row = m0 + r0 + i;
    if (row < M) {
      float* cp = C + (size_t)row * 256 + c0;  // ldc = 256
#pragma unroll
      for (int j = 0; j < 8; j++)
        cp[j] = fmaxf(acc[i][j] + bias[c0 + j], 0.0f);
    }
  }
}

// ---- edge MLP as tiled GEMM over 64-edge (CSR-ordered) tiles ----
// phase A: V[c][r] = relu(Ps[s][c] + Pd[d][c] + attr@Wa[c] + b1[c]) in LDS
// phase B: U = V^T @ W2 (micro 4x4), epilogue relu + @w3 reduce, scatter out.
__global__ __launch_bounds__(256) void edge_gemm_kernel(
    const float* __restrict__ Pcat, const uint2* __restrict__ csr2,
    const float* __restrict__ attr, const float* __restrict__ w_e1,
    const float* __restrict__ b_e1, const float* __restrict__ w_e2,
    const float* __restrict__ b_e2, const float* __restrict__ w_e3,
    const float* __restrict__ b_e3, float* __restrict__ out, int E) {
  __shared__ float sVT[128][68];   // V transposed [k][edge], pad->2-way free
  __shared__ float sW2[128][68];   // W2 [k][col]
  __shared__ float sWa[512];
  __shared__ float sB1[128];
  __shared__ float sW3[64];
  __shared__ int sEid[64];
  __shared__ float sPart[16][64];

  int tid = threadIdx.x;
  // one-time per-block staging (persistent blocks)
  for (int i = tid; i < 128 * 64; i += 256) sW2[i >> 6][i & 63] = w_e2[i];
  for (int i = tid; i < 512; i += 256) sWa[i] = w_e1[256 * 128 + i];
  if (tid < 128) sB1[tid] = b_e1[tid];
  if (tid < 64) sW3[tid] = w_e3[tid];

  int r = tid >> 2;        // phase A: edge slot in tile (0..63)
  int q = tid & 3;         // phase A: col quarter (32 cols each)
  int eg = tid & 15, cg = tid >> 4;
  int r0 = eg * 4, c0 = cg * 4;
  float be2[4];
#pragma unroll
  for (int j = 0; j < 4; j++) be2[j] = b_e2[c0 + j];
  float b3 = b_e3[0];

  for (int base = blockIdx.x * 64; base < E; base += gridDim.x * 64) {
    __syncthreads();  // covers staging + previous tile's phase-B reads
    // ---- phase A
    int slot = base + r;
    if (slot < E) {
      uint2 pk = csr2[slot];
      unsigned long long v = ((unsigned long long)pk.y << 32) | pk.x;
      int s = (int)(v & NMASK);
      int d = (int)((v >> 17) & NMASK);
      int eid = (int)(v >> 34);
      if (q == 0) sEid[r] = eid;
      const float4* ps = (const float4*)(Pcat + (size_t)s * 256 + q * 32);
      const float4* pd = (const float4*)(Pcat + (size_t)d * 256 + 128 + q * 32);
      float4 a4 = *(const float4*)(attr + (size_t)eid * 4);
#pragma unroll
      for (int j = 0; j < 8; j++) {
        float4 u = ps[j];
        float4 w = pd[j];
        int c = q * 32 + j * 4;
#pragma unroll
        for (int t = 0; t < 4; t++) {
          float uu = (t == 0) ? u.x : (t == 1) ? u.y : (t == 2) ? u.z : u.w;
          float ww = (t == 0) ? w.x : (t == 1) ? w.y : (t == 2) ? w.z : w.w;
          int cc = c + t;
          float o = uu + ww + sB1[cc] + a4.x * sWa[cc] + a4.y * sWa[128 + cc] +
                    a4.z * sWa[256 + cc] + a4.w * sWa[384 + cc];
          sVT[cc][r] = fmaxf(o, 0.0f);
        }
      }
    }
    __syncthreads();
    // ---- phase B: 64x64 GEMM, micro 4x4
    float acc[4][4];
#pragma unroll
    for (int i = 0; i < 4; i++)
#pragma unroll
      for (int j = 0; j < 4; j++) acc[i][j] = 0.0f;
#pragma unroll 8
    for (int k = 0; k < 128; k++) {
      float4 a = *(const float4*)&sVT[k][r0];
      float4 b = *(const float4*)&sW2[k][c0];
      float av[4] = {a.x, a.y, a.z, a.w};
      float bv[4] = {b.x, b.y, b.z, b.w};
#pragma unroll
      for (int i = 0; i < 4; i++)
#pragma unroll
        for (int j = 0; j < 4; j++) acc[i][j] += av[i] * bv[j];
    }
    // epilogue: relu + e3 dot (partial over this thread's 4 cols)
#pragma unroll
    for (int i = 0; i < 4; i++) {
      float p = 0.0f;
#pragma unroll
      for (int j = 0; j < 4; j++)
        p += fmaxf(acc[i][j] + be2[j], 0.0f) * sW3[c0 + j];
      sPart[cg][r0 + i] = p;
    }
    __syncthreads();
    if (tid < 64) {
      float t = 0.0f;
#pragma unroll
      for (int j = 0; j < 16; j++) t += sPart[j][tid];
      int slot2 = base + tid;
      if (slot2 < E) out[sEid[tid]] = t + b3;
    }
  }
}

extern "C" void kernel_launch(void* const* d_in, const int* in_sizes, int n_in,
                              void* d_out, int out_size, void* d_ws,
                              size_t ws_size, hipStream_t stream) {
  const float* x        = (const float*)d_in[0];
  const int*   ei       = (const int*)d_in[1];
  const float* attr     = (const float*)d_in[2];
  const float* w1_root  = (const float*)d_in[3];
  const float* w1_neigh = (const float*)d_in[4];
  const float* b1       = (const float*)d_in[5];
  const float* w2_root  = (const float*)d_in[6];
  const float* w2_neigh = (const float*)d_in[7];
  const float* b2       = (const float*)d_in[8];
  const float* w_e1     = (const float*)d_in[9];
  const float* b_e1     = (const float*)d_in[10];
  const float* w_e2     = (const float*)d_in[11];
  const float* b_e2     = (const float*)d_in[12];
  const float* w_e3     = (const float*)d_in[13];
  const float* b_e3     = (const float*)d_in[14];
  float* out = (float*)d_out;

  int N = in_sizes[0] / 6;
  int E = in_sizes[2] / 4;
  int NBLK = (N + 255) / 256;  // 391

  int* wsi = (int*)d_ws;
  int*   rowptr  = wsi;                       // [N+1]
  int*   cursor  = wsi + 100004;              // [N]
  int*   partial = wsi + 200004;              // [512]
  uint2* csr2    = (uint2*)(wsi + 200516);    // [E] x 8B
  float* cat2    = (float*)(wsi + 3400516);   // [N,256]
  float* mean1   = (float*)(wsi + 29000516);  // [N,6]

  hipMemsetAsync(cursor, 0, (size_t)N * sizeof(int), stream);

  // CSR build (by dst)
  hist_kernel<<<(E + 255) / 256, 256, 0, stream>>>(ei, cursor, E);
  scan_block_sums<<<NBLK, 256, 0, stream>>>(cursor, partial, N);
  scan_partials<<<1, 512, 0, stream>>>(partial, rowptr, NBLK, E, N);
  scan_final<<<NBLK, 256, 0, stream>>>(partial, cursor, rowptr, N);
  scatter_csr<<<(E + 255) / 256, 256, 0, stream>>>(ei, cursor, csr2, E);

  // layer 1
  agg1_kernel<<<NBLK, 256, 0, stream>>>(x, rowptr, csr2, mean1, N);
  dense1_kernel<<<N, 128, 0, stream>>>(x, mean1, w1_root, w1_neigh, b1, cat2, N);

  // layer 2 aggregation (gather, no atomics)
  agg2_kernel<<<(N + 3) / 4, 256, 0, stream>>>(cat2, cat2, rowptr, csr2, N);

  // h2 = relu([h1|mean2] @ [w2_root;w2_neigh] + b2), in-place into cols 128..255
  int gblocks = (N + 63) / 64;
  gemm_k256_n128<<<gblocks, 256, 0, stream>>>(cat2, w2_root, w2_neigh, b2,
                                              cat2 + 128, N);

  // Pcat: cols 0..127 = h2 @ Ws ; cols 128..255 = h2 @ Wd (in-place safe)
  gemm_k128_n128<false, false><<<gblocks, 256, 0, stream>>>(
      cat2 + 128, 256, w_e1, nullptr, cat2, 256, N);
  gemm_k128_n128<false, false><<<gblocks, 256, 0, stream>>>(
      cat2 + 128, 256, w_e1 + 128 * 128, nullptr, cat2 + 128, 256, N);

  // fused edge MLP (persistent: 2 blocks/CU x 256 CUs)
  edge_gemm_kernel<<<512, 256, 0, stream>>>(cat2, csr2, attr, w_e1, b_e1, w_e2,
                                            b_e2, w_e3, b_e3, out, E);
}

// Round 3
// 755.026 us; speedup vs baseline: 3.3816x; 1.4874x over previous
//
#include <hip/hip_runtime.h>
#include <hip/hip_bf16.h>
#include <stdint.h>

// ---------------------------------------------------------------------------
// UVSeamGNN R3: bf16 MFMA everywhere GEMM-shaped; bf16 activations for gathers.
//   e1 factorization: [h[s],h[d],attr]@W1 = Ps[s] + (Pd+b1)[d] + attr@Wa
// Workspace (4B words), N=100000, E=1600000:
//   rowptr [N+1]      @ 0
//   cursor [N]        @ 100004
//   partial[512]      @ 200004
//   csr2   [E]x8B     @ 200520   (src | dst<<17 | eid<<34)
//   mean1  [N*6] f32  @ 3400520
//   cat2b  [N][256]b  @ 4000520  (cols 0..127: h1 then Ps; 128..255: mean2 then Pd+b1)
//   h2b    [N][128]b  @ 16800520
//   B2f    [32768]u16 @ 23200520 (frag-packed [w2_root;w2_neigh], KT8 NT8)
//   WSDf   [32768]u16 @ 23216904 (frag-packed [Ws|Wd], KT4 NT16)
//   W2f    [8192]u16  @ 23233288 (frag-packed w_e2, KT4 NT4)
//   pbias  [256] f32  @ 23237384 (0..127: 0, 128..255: b_e1)
// total ~93 MB
// ---------------------------------------------------------------------------

typedef unsigned short u16;
typedef short bf16x8 __attribute__((ext_vector_type(8)));
typedef float f32x4 __attribute__((ext_vector_type(4)));

#define NMASK 0x1FFFF

__device__ __forceinline__ u16 f2b(float f) {
  unsigned u = __builtin_bit_cast(unsigned, f);
  u = u + 0x7fffu + ((u >> 16) & 1u);
  return (u16)(u >> 16);
}
__device__ __forceinline__ float bflo(unsigned u) {
  return __builtin_bit_cast(float, u << 16);
}
__device__ __forceinline__ float bfhi(unsigned u) {
  return __builtin_bit_cast(float, u & 0xffff0000u);
}
__device__ __forceinline__ unsigned pack2bf(float a, float b) {
  unsigned ua = __builtin_bit_cast(unsigned, a);
  unsigned ub = __builtin_bit_cast(unsigned, b);
  ua = ua + 0x7fffu + ((ua >> 16) & 1u);
  ub = ub + 0x7fffu + ((ub >> 16) & 1u);
  return (ua >> 16) | (ub & 0xffff0000u);
}

// ---- CSR build ----
__global__ void hist_kernel(const int* __restrict__ ei, int* __restrict__ cnt,
                            int E) {
  int e = blockIdx.x * blockDim.x + threadIdx.x;
  if (e < E) atomicAdd(&cnt[ei[E + e]], 1);
}

__global__ void scan_block_sums(const int* __restrict__ cnt,
                                int* __restrict__ partial, int N) {
  __shared__ int red[256];
  int t = threadIdx.x;
  int n = blockIdx.x * 256 + t;
  red[t] = (n < N) ? cnt[n] : 0;
  __syncthreads();
  for (int off = 128; off; off >>= 1) {
    if (t < off) red[t] += red[t + off];
    __syncthreads();
  }
  if (t == 0) partial[blockIdx.x] = red[0];
}

__global__ void scan_partials(int* __restrict__ partial,
                              int* __restrict__ rowptr, int NBLK, int E,
                              int N) {
  __shared__ int sc[512];
  int t = threadIdx.x;
  int v = (t < NBLK) ? partial[t] : 0;
  sc[t] = v;
  __syncthreads();
  for (int off = 1; off < 512; off <<= 1) {
    int a = (t >= off) ? sc[t - off] : 0;
    __syncthreads();
    sc[t] += a;
    __syncthreads();
  }
  if (t < NBLK) partial[t] = sc[t] - v;  // exclusive
  if (t == 0) rowptr[N] = E;
}

__global__ void scan_final(const int* __restrict__ partial,
                           int* __restrict__ cursor, int* __restrict__ rowptr,
                           int N) {
  __shared__ int sc[256];
  int t = threadIdx.x;
  int n = blockIdx.x * 256 + t;
  int v = (n < N) ? cursor[n] : 0;
  sc[t] = v;
  __syncthreads();
  for (int off = 1; off < 256; off <<= 1) {
    int a = (t >= off) ? sc[t - off] : 0;
    __syncthreads();
    sc[t] += a;
    __syncthreads();
  }
  int excl = partial[blockIdx.x] + sc[t] - v;
  if (n < N) {
    rowptr[n] = excl;
    cursor[n] = excl;
  }
}

__global__ void scatter_csr(const int* __restrict__ ei,
                            int* __restrict__ cursor, uint2* __restrict__ csr2,
                            int E) {
  int e = blockIdx.x * blockDim.x + threadIdx.x;
  if (e >= E) return;
  int s = ei[e];
  int d = ei[E + e];
  int pos = atomicAdd(&cursor[d], 1);
  unsigned long long v = (unsigned long long)(unsigned)s |
                         ((unsigned long long)(unsigned)d << 17) |
                         ((unsigned long long)(unsigned)e << 34);
  csr2[pos] = make_uint2((unsigned)v, (unsigned)(v >> 32));
}

// ---- pack weights into bf16 MFMA B-fragment layouts ----
// B-frag element for lane l, j: B[k = kt*32 + (l>>4)*8 + j][n = nt*16 + (l&15)]
__global__ void pack_weights(const float* __restrict__ w2_root,
                             const float* __restrict__ w2_neigh,
                             const float* __restrict__ w_e1,
                             const float* __restrict__ w_e2,
                             const float* __restrict__ b_e1,
                             u16* __restrict__ B2f, u16* __restrict__ WSDf,
                             u16* __restrict__ W2f, float* __restrict__ pbias) {
  int t = blockIdx.x * 256 + threadIdx.x;
  if (t < 32768) {  // B2f: KT=8, NT=8 over [w2_root; w2_neigh] (K=256, N=128)
    int j = t & 7, lane = (t >> 3) & 63, nt = (t >> 9) & 7, kt = t >> 12;
    int k = kt * 32 + (lane >> 4) * 8 + j;
    int n = nt * 16 + (lane & 15);
    float v = (k < 128) ? w2_root[k * 128 + n] : w2_neigh[(k - 128) * 128 + n];
    B2f[t] = f2b(v);
  } else if (t < 65536) {  // WSDf: KT=4, NT=16 over [Ws | Wd] (K=128, N=256)
    int t2 = t - 32768;
    int j = t2 & 7, lane = (t2 >> 3) & 63, nt = (t2 >> 9) & 15, kt = t2 >> 13;
    int k = kt * 32 + (lane >> 4) * 8 + j;
    int n = nt * 16 + (lane & 15);
    float v = (n < 128) ? w_e1[k * 128 + n] : w_e1[(128 + k) * 128 + (n - 128)];
    WSDf[t2] = f2b(v);
  } else if (t < 73728) {  // W2f: KT=4, NT=4 over w_e2 (K=128, N=64)
    int t2 = t - 65536;
    int j = t2 & 7, lane = (t2 >> 3) & 63, nt = (t2 >> 9) & 3, kt = t2 >> 11;
    int k = kt * 32 + (lane >> 4) * 8 + j;
    int n = nt * 16 + (lane & 15);
    W2f[t2] = f2b(w_e2[k * 64 + n]);
  } else if (t < 73984) {  // pbias
    int n = t - 73728;
    pbias[n] = (n < 128) ? 0.0f : b_e1[n - 128];
  }
}

// ---- layer-1 mean aggregation ----
__global__ void agg1_kernel(const float* __restrict__ x,
                            const int* __restrict__ rowptr,
                            const uint2* __restrict__ csr2,
                            float* __restrict__ mean1, int N) {
  int n = blockIdx.x * blockDim.x + threadIdx.x;
  if (n >= N) return;
  int beg = rowptr[n], end = rowptr[n + 1];
  float s0 = 0, s1 = 0, s2 = 0, s3 = 0, s4 = 0, s5 = 0;
  for (int i = beg; i < end; i++) {
    int s = (int)(csr2[i].x & NMASK);
    const float2* xp = (const float2*)(x + (size_t)s * 6);
    float2 a = xp[0], b = xp[1], c = xp[2];
    s0 += a.x; s1 += a.y; s2 += b.x; s3 += b.y; s4 += c.x; s5 += c.y;
  }
  float inv = 1.0f / (float)max(end - beg, 1);
  float* mp = mean1 + (size_t)n * 6;
  mp[0] = s0 * inv; mp[1] = s1 * inv; mp[2] = s2 * inv;
  mp[3] = s3 * inv; mp[4] = s4 * inv; mp[5] = s5 * inv;
}

// ---- dense layer 1 -> h1 bf16 into cat2b cols 0..127 ----
__global__ void dense1_kernel(const float* __restrict__ x,
                              const float* __restrict__ mean1,
                              const float* __restrict__ w_root,
                              const float* __restrict__ w_neigh,
                              const float* __restrict__ b,
                              u16* __restrict__ cat2b, int N) {
  int n = blockIdx.x;
  int m = threadIdx.x;
  if (n >= N) return;
  float s = b[m];
#pragma unroll
  for (int j = 0; j < 6; j++) {
    s += x[(size_t)n * 6 + j] * w_root[j * 128 + m] +
         mean1[(size_t)n * 6 + j] * w_neigh[j * 128 + m];
  }
  cat2b[(size_t)n * 256 + m] = f2b(fmaxf(s, 0.0f));
}

// ---- layer-2 mean aggregation (bf16 gather, fp32 sum, bf16 write) ----
__global__ __launch_bounds__(256) void agg2_kernel(
    const u16* __restrict__ cat2b, u16* __restrict__ cat2w,
    const int* __restrict__ rowptr, const uint2* __restrict__ csr2, int N) {
  int n = blockIdx.x * 4 + (threadIdx.x >> 6);
  int lane = threadIdx.x & 63;
  if (n >= N) return;
  int beg = rowptr[n], end = rowptr[n + 1];
  float a0 = 0.0f, a1 = 0.0f;
  int i = beg;
  for (; i + 2 <= end; i += 2) {
    int s0 = (int)(csr2[i].x & NMASK);
    int s1 = (int)(csr2[i + 1].x & NMASK);
    unsigned u0 = *(const unsigned*)(cat2b + (size_t)s0 * 256 + lane * 2);
    unsigned u1 = *(const unsigned*)(cat2b + (size_t)s1 * 256 + lane * 2);
    a0 += bflo(u0) + bflo(u1);
    a1 += bfhi(u0) + bfhi(u1);
  }
  if (i < end) {
    int s = (int)(csr2[i].x & NMASK);
    unsigned u = *(const unsigned*)(cat2b + (size_t)s * 256 + lane * 2);
    a0 += bflo(u);
    a1 += bfhi(u);
  }
  float inv = 1.0f / (float)max(end - beg, 1);
  *(unsigned*)(cat2w + (size_t)n * 256 + 128 + lane * 2) =
      pack2bf(a0 * inv, a1 * inv);
}

// ---- bf16 MFMA GEMM: C[M,NT*16] = op(A[M,KT*32] @ Bfrag + bias) ----
// block 256 = 4 waves; wave w owns rows [blk*64 + w*16, +16). B staged in LDS.
template <int KT, int NT, bool RELU>
__global__ __launch_bounds__(256) void mfma_gemm(
    const u16* __restrict__ A, int lda, const u16* __restrict__ Bf,
    const float* __restrict__ bias, u16* __restrict__ C, int ldc, int M) {
  __shared__ u16 sB[KT * NT * 512];
  int tid = threadIdx.x;
  for (int i = tid; i < KT * NT * 64; i += 256)
    ((uint4*)sB)[i] = ((const uint4*)Bf)[i];
  int w = tid >> 6, l = tid & 63;
  int quad = l >> 4, col16 = l & 15;
  int rowA = blockIdx.x * 64 + w * 16 + col16;
  bool rv = rowA < M;
  const u16* ap = A + (size_t)rowA * lda + quad * 8;
  f32x4 acc[NT];
#pragma unroll
  for (int nt = 0; nt < NT; nt++) acc[nt] = (f32x4){0.f, 0.f, 0.f, 0.f};
  __syncthreads();
#pragma unroll
  for (int kt = 0; kt < KT; kt++) {
    bf16x8 av = {};
    if (rv) av = *(const bf16x8*)(ap + kt * 32);
#pragma unroll
    for (int nt = 0; nt < NT; nt++) {
      bf16x8 bv = *(const bf16x8*)(sB + ((kt * NT + nt) * 64 + l) * 8);
      acc[nt] = __builtin_amdgcn_mfma_f32_16x16x32_bf16(av, bv, acc[nt], 0, 0, 0);
    }
  }
  int rowbase = blockIdx.x * 64 + w * 16 + quad * 4;
#pragma unroll
  for (int r = 0; r < 4; r++) {
    int row = rowbase + r;
    if (row < M) {
#pragma unroll
      for (int nt = 0; nt < NT; nt++) {
        float v = acc[nt][r] + bias[nt * 16 + col16];
        if (RELU) v = fmaxf(v, 0.0f);
        C[(size_t)row * ldc + nt * 16 + col16] = f2b(v);
      }
    }
  }
}

// ---- edge MLP: phase A build V bf16 in LDS; phase B MFMA vs reg-resident W2 ----
__global__ __launch_bounds__(256) void edge_mfma_kernel(
    const u16* __restrict__ Pcatb, const uint2* __restrict__ csr2,
    const float* __restrict__ attr, const float* __restrict__ w_e1,
    const u16* __restrict__ W2f, const float* __restrict__ b_e2,
    const float* __restrict__ w_e3, const float* __restrict__ b_e3,
    float* __restrict__ out, int E) {
  __shared__ u16 sV[64 * 136];  // V[64 edges][128 cols], pitch 136 (16B align)
  __shared__ uint2 sPk[64];

  int tid = threadIdx.x;
  int w = tid >> 6, l = tid & 63, quad = l >> 4, c16 = l & 15;
  int egrp = tid >> 4, ac16 = tid & 15;

  // W2 B-fragments in registers (tile-invariant)
  bf16x8 w2f[4][4];
#pragma unroll
  for (int kt = 0; kt < 4; kt++)
#pragma unroll
    for (int nt = 0; nt < 4; nt++)
      w2f[kt][nt] = *(const bf16x8*)(W2f + ((kt * 4 + nt) * 64 + l) * 8);
  // Wa (attr rows of w_e1) for this lane's 8 phase-A columns
  float wa[4][8];
#pragma unroll
  for (int j = 0; j < 4; j++) {
    *(float4*)&wa[j][0] = *(const float4*)(w_e1 + (256 + j) * 128 + ac16 * 8);
    *(float4*)&wa[j][4] = *(const float4*)(w_e1 + (256 + j) * 128 + ac16 * 8 + 4);
  }
  float w3v[4], be2[4];
#pragma unroll
  for (int nt = 0; nt < 4; nt++) {
    w3v[nt] = w_e3[nt * 16 + c16];
    be2[nt] = b_e2[nt * 16 + c16];
  }
  float b3 = b_e3[0];

  for (int base = blockIdx.x * 64; base < E; base += gridDim.x * 64) {
    __syncthreads();  // protect sV/sPk reuse across tiles
    if (tid < 64 && base + tid < E) sPk[tid] = csr2[base + tid];
    __syncthreads();
    // ---- phase A: V[e][c] = relu(Ps[s][c] + Pdb[d][c] + attr@Wa[c])
#pragma unroll
    for (int it = 0; it < 4; it++) {
      int e = it * 16 + egrp;
      if (base + e < E) {
        uint2 pk = sPk[e];
        unsigned long long v = ((unsigned long long)pk.y << 32) | pk.x;
        int s = (int)(v & NMASK);
        int d = (int)((v >> 17) & NMASK);
        int eid = (int)(v >> 34);
        uint4 psu = *(const uint4*)(Pcatb + (size_t)s * 256 + ac16 * 8);
        uint4 pdu = *(const uint4*)(Pcatb + (size_t)d * 256 + 128 + ac16 * 8);
        float4 a4 = *(const float4*)(attr + (size_t)eid * 4);
        unsigned pu[4] = {psu.x, psu.y, psu.z, psu.w};
        unsigned du[4] = {pdu.x, pdu.y, pdu.z, pdu.w};
        uint4 ov;
        unsigned* op = (unsigned*)&ov;
#pragma unroll
        for (int p2 = 0; p2 < 4; p2++) {
          int t0 = p2 * 2, t1 = t0 + 1;
          float f0 = bflo(pu[p2]) + bflo(du[p2]);
          float f1 = bfhi(pu[p2]) + bfhi(du[p2]);
          f0 += a4.x * wa[0][t0] + a4.y * wa[1][t0] + a4.z * wa[2][t0] +
                a4.w * wa[3][t0];
          f1 += a4.x * wa[0][t1] + a4.y * wa[1][t1] + a4.z * wa[2][t1] +
                a4.w * wa[3][t1];
          op[p2] = pack2bf(fmaxf(f0, 0.0f), fmaxf(f1, 0.0f));
        }
        *(uint4*)(sV + e * 136 + ac16 * 8) = ov;
      }
    }
    __syncthreads();
    // ---- phase B: U = V @ W2 via MFMA; epilogue relu + @w3 reduce
    f32x4 acc[4];
#pragma unroll
    for (int nt = 0; nt < 4; nt++) acc[nt] = (f32x4){0.f, 0.f, 0.f, 0.f};
    const u16* vp = sV + (w * 16 + c16) * 136 + quad * 8;
#pragma unroll
    for (int kt = 0; kt < 4; kt++) {
      bf16x8 av = *(const bf16x8*)(vp + kt * 32);
#pragma unroll
      for (int nt = 0; nt < 4; nt++)
        acc[nt] = __builtin_amdgcn_mfma_f32_16x16x32_bf16(av, w2f[kt][nt],
                                                          acc[nt], 0, 0, 0);
    }
#pragma unroll
    for (int r = 0; r < 4; r++) {
      float p = 0.0f;
#pragma unroll
      for (int nt = 0; nt < 4; nt++)
        p += fmaxf(acc[nt][r] + be2[nt], 0.0f) * w3v[nt];
      p += __shfl_xor(p, 1, 64);
      p += __shfl_xor(p, 2, 64);
      p += __shfl_xor(p, 4, 64);
      p += __shfl_xor(p, 8, 64);
      if (c16 == 0) {
        int eloc = w * 16 + quad * 4 + r;
        if (base + eloc < E) {
          uint2 pk = sPk[eloc];
          unsigned long long vv = ((unsigned long long)pk.y << 32) | pk.x;
          out[(int)(vv >> 34)] = p + b3;
        }
      }
    }
  }
}

extern "C" void kernel_launch(void* const* d_in, const int* in_sizes, int n_in,
                              void* d_out, int out_size, void* d_ws,
                              size_t ws_size, hipStream_t stream) {
  const float* x        = (const float*)d_in[0];
  const int*   ei       = (const int*)d_in[1];
  const float* attr     = (const float*)d_in[2];
  const float* w1_root  = (const float*)d_in[3];
  const float* w1_neigh = (const float*)d_in[4];
  const float* b1       = (const float*)d_in[5];
  const float* w2_root  = (const float*)d_in[6];
  const float* w2_neigh = (const float*)d_in[7];
  const float* b2       = (const float*)d_in[8];
  const float* w_e1     = (const float*)d_in[9];
  const float* b_e1     = (const float*)d_in[10];
  const float* w_e2     = (const float*)d_in[11];
  const float* b_e2     = (const float*)d_in[12];
  const float* w_e3     = (const float*)d_in[13];
  const float* b_e3     = (const float*)d_in[14];
  float* out = (float*)d_out;

  int N = in_sizes[0] / 6;
  int E = in_sizes[2] / 4;
  int NBLK = (N + 255) / 256;

  int* wsi = (int*)d_ws;
  int*   rowptr  = wsi;                        // [N+1]
  int*   cursor  = wsi + 100004;               // [N]
  int*   partial = wsi + 200004;               // [512]
  uint2* csr2    = (uint2*)(wsi + 200520);     // [E] x 8B
  float* mean1   = (float*)(wsi + 3400520);    // [N,6]
  u16*   cat2b   = (u16*)(wsi + 4000520);      // [N,256] bf16
  u16*   h2b     = (u16*)(wsi + 16800520);     // [N,128] bf16
  u16*   B2f     = (u16*)(wsi + 23200520);     // 32768
  u16*   WSDf    = (u16*)(wsi + 23216904);     // 32768
  u16*   W2f     = (u16*)(wsi + 23233288);     // 8192
  float* pbias   = (float*)(wsi + 23237384);   // 256

  hipMemsetAsync(cursor, 0, (size_t)N * sizeof(int), stream);

  pack_weights<<<289, 256, 0, stream>>>(w2_root, w2_neigh, w_e1, w_e2, b_e1,
                                        B2f, WSDf, W2f, pbias);

  // CSR build (by dst)
  hist_kernel<<<(E + 255) / 256, 256, 0, stream>>>(ei, cursor, E);
  scan_block_sums<<<NBLK, 256, 0, stream>>>(cursor, partial, N);
  scan_partials<<<1, 512, 0, stream>>>(partial, rowptr, NBLK, E, N);
  scan_final<<<NBLK, 256, 0, stream>>>(partial, cursor, rowptr, N);
  scatter_csr<<<(E + 255) / 256, 256, 0, stream>>>(ei, cursor, csr2, E);

  // layer 1
  agg1_kernel<<<NBLK, 256, 0, stream>>>(x, rowptr, csr2, mean1, N);
  dense1_kernel<<<N, 128, 0, stream>>>(x, mean1, w1_root, w1_neigh, b1, cat2b, N);

  // layer 2 aggregation (bf16 gather)
  agg2_kernel<<<(N + 3) / 4, 256, 0, stream>>>(cat2b, cat2b, rowptr, csr2, N);

  int gblocks = (N + 63) / 64;
  // h2 = relu([h1|mean2] @ [w2_root;w2_neigh] + b2)
  mfma_gemm<8, 8, true><<<gblocks, 256, 0, stream>>>(cat2b, 256, B2f, b2, h2b,
                                                     128, N);
  // Pcat = h2 @ [Ws|Wd] + [0|b_e1]
  mfma_gemm<4, 16, false><<<gblocks, 256, 0, stream>>>(h2b, 128, WSDf, pbias,
                                                       cat2b, 256, N);

  // fused edge MLP
  edge_mfma_kernel<<<4096, 256, 0, stream>>>(cat2b, csr2, attr, w_e1, W2f,
                                             b_e2, w_e3, b_e3, out, E);
}

// Round 4
// 657.630 us; speedup vs baseline: 3.8824x; 1.1481x over previous
//
#include <hip/hip_runtime.h>
#include <hip/hip_bf16.h>
#include <stdint.h>

// ---------------------------------------------------------------------------
// UVSeamGNN R4: pipelined gathers (the R3 edge/agg kernels were latency-bound:
// dur == bytes/1.83 TB/s with MfmaUtil 4%). 2-stage register prefetch +
// single-barrier double-buffered tiles; attr pre-permuted to CSR order;
// wave-parallel gather-reduce for both aggregations.
// Workspace (4B words), N=100000, E=1600000:
//   rowptr [N+1]      @ 0
//   cursor [N]        @ 100004
//   partial[512]      @ 200004
//   csr2   [E]x8B     @ 200520   (src | dst<<17 | eid<<34)
//   mean1  [N*6] f32  @ 3400520
//   cat2b  [N][256]b  @ 4000520  (cols 0..127: h1 then Ps; 128..255: mean2 then Pd+b1)
//   h2b    [N][128]b  @ 16800520
//   B2f    [32768]u16 @ 23200520 (frag-packed [w2_root;w2_neigh], KT8 NT8)
//   WSDf   [32768]u16 @ 23216904 (frag-packed [Ws|Wd], KT4 NT16)
//   W2f    [8192]u16  @ 23233288 (frag-packed w_e2, KT4 NT4)
//   pbias  [256] f32  @ 23237384 (0..127: 0, 128..255: b_e1)
//   attrp  [E*4] f32  @ 23237640 (attr permuted to CSR slot order)
// total ~118.5 MB
// ---------------------------------------------------------------------------

typedef unsigned short u16;
typedef short bf16x8 __attribute__((ext_vector_type(8)));
typedef float f32x4 __attribute__((ext_vector_type(4)));

#define NMASK 0x1FFFF

__device__ __forceinline__ u16 f2b(float f) {
  unsigned u = __builtin_bit_cast(unsigned, f);
  u = u + 0x7fffu + ((u >> 16) & 1u);
  return (u16)(u >> 16);
}
__device__ __forceinline__ float bflo(unsigned u) {
  return __builtin_bit_cast(float, u << 16);
}
__device__ __forceinline__ float bfhi(unsigned u) {
  return __builtin_bit_cast(float, u & 0xffff0000u);
}
__device__ __forceinline__ unsigned pack2bf(float a, float b) {
  unsigned ua = __builtin_bit_cast(unsigned, a);
  unsigned ub = __builtin_bit_cast(unsigned, b);
  ua = ua + 0x7fffu + ((ua >> 16) & 1u);
  ub = ub + 0x7fffu + ((ub >> 16) & 1u);
  return (ua >> 16) | (ub & 0xffff0000u);
}

// ---- CSR build ----
__global__ void hist_kernel(const int* __restrict__ ei, int* __restrict__ cnt,
                            int E) {
  int e = blockIdx.x * blockDim.x + threadIdx.x;
  if (e < E) atomicAdd(&cnt[ei[E + e]], 1);
}

__global__ void scan_block_sums(const int* __restrict__ cnt,
                                int* __restrict__ partial, int N) {
  __shared__ int red[256];
  int t = threadIdx.x;
  int n = blockIdx.x * 256 + t;
  red[t] = (n < N) ? cnt[n] : 0;
  __syncthreads();
  for (int off = 128; off; off >>= 1) {
    if (t < off) red[t] += red[t + off];
    __syncthreads();
  }
  if (t == 0) partial[blockIdx.x] = red[0];
}

__global__ void scan_partials(int* __restrict__ partial,
                              int* __restrict__ rowptr, int NBLK, int E,
                              int N) {
  __shared__ int sc[512];
  int t = threadIdx.x;
  int v = (t < NBLK) ? partial[t] : 0;
  sc[t] = v;
  __syncthreads();
  for (int off = 1; off < 512; off <<= 1) {
    int a = (t >= off) ? sc[t - off] : 0;
    __syncthreads();
    sc[t] += a;
    __syncthreads();
  }
  if (t < NBLK) partial[t] = sc[t] - v;  // exclusive
  if (t == 0) rowptr[N] = E;
}

__global__ void scan_final(const int* __restrict__ partial,
                           int* __restrict__ cursor, int* __restrict__ rowptr,
                           int N) {
  __shared__ int sc[256];
  int t = threadIdx.x;
  int n = blockIdx.x * 256 + t;
  int v = (n < N) ? cursor[n] : 0;
  sc[t] = v;
  __syncthreads();
  for (int off = 1; off < 256; off <<= 1) {
    int a = (t >= off) ? sc[t - off] : 0;
    __syncthreads();
    sc[t] += a;
    __syncthreads();
  }
  int excl = partial[blockIdx.x] + sc[t] - v;
  if (n < N) {
    rowptr[n] = excl;
    cursor[n] = excl;
  }
}

__global__ void scatter_csr(const int* __restrict__ ei,
                            int* __restrict__ cursor, uint2* __restrict__ csr2,
                            int E) {
  int e = blockIdx.x * blockDim.x + threadIdx.x;
  if (e >= E) return;
  int s = ei[e];
  int d = ei[E + e];
  int pos = atomicAdd(&cursor[d], 1);
  unsigned long long v = (unsigned long long)(unsigned)s |
                         ((unsigned long long)(unsigned)d << 17) |
                         ((unsigned long long)(unsigned)e << 34);
  csr2[pos] = make_uint2((unsigned)v, (unsigned)(v >> 32));
}

// ---- permute attr into CSR slot order (sequential writes, one-time gather) --
__global__ void permute_attr(const float* __restrict__ attr,
                             const uint2* __restrict__ csr2,
                             float4* __restrict__ attrp, int E) {
  int i = blockIdx.x * 256 + threadIdx.x;
  if (i >= E) return;
  uint2 pk = csr2[i];
  int eid = (int)((((unsigned long long)pk.y << 32) | pk.x) >> 34);
  attrp[i] = *(const float4*)(attr + (size_t)eid * 4);
}

// ---- pack weights into bf16 MFMA B-fragment layouts ----
__global__ void pack_weights(const float* __restrict__ w2_root,
                             const float* __restrict__ w2_neigh,
                             const float* __restrict__ w_e1,
                             const float* __restrict__ w_e2,
                             const float* __restrict__ b_e1,
                             u16* __restrict__ B2f, u16* __restrict__ WSDf,
                             u16* __restrict__ W2f, float* __restrict__ pbias) {
  int t = blockIdx.x * 256 + threadIdx.x;
  if (t < 32768) {  // B2f: KT=8, NT=8 over [w2_root; w2_neigh] (K=256, N=128)
    int j = t & 7, lane = (t >> 3) & 63, nt = (t >> 9) & 7, kt = t >> 12;
    int k = kt * 32 + (lane >> 4) * 8 + j;
    int n = nt * 16 + (lane & 15);
    float v = (k < 128) ? w2_root[k * 128 + n] : w2_neigh[(k - 128) * 128 + n];
    B2f[t] = f2b(v);
  } else if (t < 65536) {  // WSDf: KT=4, NT=16 over [Ws | Wd] (K=128, N=256)
    int t2 = t - 32768;
    int j = t2 & 7, lane = (t2 >> 3) & 63, nt = (t2 >> 9) & 15, kt = t2 >> 13;
    int k = kt * 32 + (lane >> 4) * 8 + j;
    int n = nt * 16 + (lane & 15);
    float v = (n < 128) ? w_e1[k * 128 + n] : w_e1[(128 + k) * 128 + (n - 128)];
    WSDf[t2] = f2b(v);
  } else if (t < 73728) {  // W2f: KT=4, NT=4 over w_e2 (K=128, N=64)
    int t2 = t - 65536;
    int j = t2 & 7, lane = (t2 >> 3) & 63, nt = (t2 >> 9) & 3, kt = t2 >> 11;
    int k = kt * 32 + (lane >> 4) * 8 + j;
    int n = nt * 16 + (lane & 15);
    W2f[t2] = f2b(w_e2[k * 64 + n]);
  } else if (t < 73984) {  // pbias
    int n = t - 73728;
    pbias[n] = (n < 128) ? 0.0f : b_e1[n - 128];
  }
}

// ---- layer-1 mean aggregation: wave per node, 8 rows x 8 lanes ----
__global__ __launch_bounds__(256) void agg1_kernel(
    const float* __restrict__ x, const int* __restrict__ rowptr,
    const uint2* __restrict__ csr2, float* __restrict__ mean1, int N) {
  int n = blockIdx.x * 4 + (threadIdx.x >> 6);
  if (n >= N) return;
  int lane = threadIdx.x & 63;
  int g = lane >> 3;  // row group 0..7
  int c = lane & 7;   // col 0..7 (0..5 valid)
  int beg = rowptr[n], end = rowptr[n + 1];
  float a = 0.0f;
  if (c < 6) {
    for (int i = beg + g; i < end; i += 8) {
      int s = (int)(csr2[i].x & NMASK);
      a += x[(size_t)s * 6 + c];
    }
  }
  a += __shfl_xor(a, 8, 64);
  a += __shfl_xor(a, 16, 64);
  a += __shfl_xor(a, 32, 64);
  if (g == 0 && c < 6)
    mean1[(size_t)n * 6 + c] = a / (float)max(end - beg, 1);
}

// ---- dense layer 1 -> h1 bf16 into cat2b cols 0..127 ----
__global__ void dense1_kernel(const float* __restrict__ x,
                              const float* __restrict__ mean1,
                              const float* __restrict__ w_root,
                              const float* __restrict__ w_neigh,
                              const float* __restrict__ b,
                              u16* __restrict__ cat2b, int N) {
  int n = blockIdx.x;
  int m = threadIdx.x;
  if (n >= N) return;
  float s = b[m];
#pragma unroll
  for (int j = 0; j < 6; j++) {
    s += x[(size_t)n * 6 + j] * w_root[j * 128 + m] +
         mean1[(size_t)n * 6 + j] * w_neigh[j * 128 + m];
  }
  cat2b[(size_t)n * 256 + m] = f2b(fmaxf(s, 0.0f));
}

// ---- layer-2 mean aggregation: wave per node, 4 rows x 16 lanes x uint4 ----
__global__ __launch_bounds__(256) void agg2_kernel(
    const u16* __restrict__ cat2b, u16* __restrict__ cat2w,
    const int* __restrict__ rowptr, const uint2* __restrict__ csr2, int N) {
  int n = blockIdx.x * 4 + (threadIdx.x >> 6);
  if (n >= N) return;
  int lane = threadIdx.x & 63;
  int g = lane >> 4;  // row group 0..3
  int c = lane & 15;  // col chunk (8 bf16)
  int beg = rowptr[n], end = rowptr[n + 1];
  float acc[8];
#pragma unroll
  for (int j = 0; j < 8; j++) acc[j] = 0.0f;
  for (int i = beg + g; i < end; i += 4) {
    int s = (int)(csr2[i].x & NMASK);
    uint4 u = *(const uint4*)(cat2b + (size_t)s * 256 + c * 8);
    acc[0] += bflo(u.x); acc[1] += bfhi(u.x);
    acc[2] += bflo(u.y); acc[3] += bfhi(u.y);
    acc[4] += bflo(u.z); acc[5] += bfhi(u.z);
    acc[6] += bflo(u.w); acc[7] += bfhi(u.w);
  }
#pragma unroll
  for (int j = 0; j < 8; j++) {
    acc[j] += __shfl_xor(acc[j], 16, 64);
    acc[j] += __shfl_xor(acc[j], 32, 64);
  }
  if (g == 0) {
    float inv = 1.0f / (float)max(end - beg, 1);
    uint4 ov;
    ov.x = pack2bf(acc[0] * inv, acc[1] * inv);
    ov.y = pack2bf(acc[2] * inv, acc[3] * inv);
    ov.z = pack2bf(acc[4] * inv, acc[5] * inv);
    ov.w = pack2bf(acc[6] * inv, acc[7] * inv);
    *(uint4*)(cat2w + (size_t)n * 256 + 128 + c * 8) = ov;
  }
}

// ---- bf16 MFMA GEMM: C[M,NT*16] = op(A[M,KT*32] @ Bfrag + bias) ----
template <int KT, int NT, bool RELU>
__global__ __launch_bounds__(256) void mfma_gemm(
    const u16* __restrict__ A, int lda, const u16* __restrict__ Bf,
    const float* __restrict__ bias, u16* __restrict__ C, int ldc, int M) {
  __shared__ u16 sB[KT * NT * 512];
  int tid = threadIdx.x;
  for (int i = tid; i < KT * NT * 64; i += 256)
    ((uint4*)sB)[i] = ((const uint4*)Bf)[i];
  int w = tid >> 6, l = tid & 63;
  int quad = l >> 4, col16 = l & 15;
  int rowA = blockIdx.x * 64 + w * 16 + col16;
  bool rv = rowA < M;
  const u16* ap = A + (size_t)rowA * lda + quad * 8;
  f32x4 acc[NT];
#pragma unroll
  for (int nt = 0; nt < NT; nt++) acc[nt] = (f32x4){0.f, 0.f, 0.f, 0.f};
  __syncthreads();
#pragma unroll
  for (int kt = 0; kt < KT; kt++) {
    bf16x8 av = {};
    if (rv) av = *(const bf16x8*)(ap + kt * 32);
#pragma unroll
    for (int nt = 0; nt < NT; nt++) {
      bf16x8 bv = *(const bf16x8*)(sB + ((kt * NT + nt) * 64 + l) * 8);
      acc[nt] = __builtin_amdgcn_mfma_f32_16x16x32_bf16(av, bv, acc[nt], 0, 0, 0);
    }
  }
  int rowbase = blockIdx.x * 64 + w * 16 + quad * 4;
#pragma unroll
  for (int r = 0; r < 4; r++) {
    int row = rowbase + r;
    if (row < M) {
#pragma unroll
      for (int nt = 0; nt < NT; nt++) {
        float v = acc[nt][r] + bias[nt * 16 + col16];
        if (RELU) v = fmaxf(v, 0.0f);
        C[(size_t)row * ldc + nt * 16 + col16] = f2b(v);
      }
    }
  }
}

// ---- pipelined edge MLP ----
// per-tile: phase A (from prefetched regs) -> sV[buf]; issue t+S gathers;
// one barrier; phase B MFMA from LDS. eid rides in sV row padding.
__global__ __launch_bounds__(256) void edge_mfma_kernel(
    const u16* __restrict__ Pcatb, const uint2* __restrict__ csr2,
    const float4* __restrict__ attrp, const float* __restrict__ w_e1,
    const u16* __restrict__ W2f, const float* __restrict__ b_e2,
    const float* __restrict__ w_e3, const float* __restrict__ b_e3,
    float* __restrict__ out, int E) {
  __shared__ u16 sV[2][64 * 136];  // cols 0..127 = V, u16 slot 128.. = eid
  __shared__ u16 sW2[8192];

  int tid = threadIdx.x;
  int w = tid >> 6, l = tid & 63, quad = l >> 4, c16 = l & 15;
  int egrp = tid >> 4, ac16 = tid & 15;

  for (int i = tid; i < 1024; i += 256)
    ((uint4*)sW2)[i] = ((const uint4*)W2f)[i];

  float wa[4][8];
#pragma unroll
  for (int j = 0; j < 4; j++) {
    *(float4*)&wa[j][0] = *(const float4*)(w_e1 + (256 + j) * 128 + ac16 * 8);
    *(float4*)&wa[j][4] = *(const float4*)(w_e1 + (256 + j) * 128 + ac16 * 8 + 4);
  }
  float w3v[4], be2[4];
#pragma unroll
  for (int nt = 0; nt < 4; nt++) {
    w3v[nt] = w_e3[nt * 16 + c16];
    be2[nt] = b_e2[nt * 16 + c16];
  }
  float b3 = b_e3[0];

  int tiles = (E + 63) >> 6;
  int S = gridDim.x;

  uint2 pk[4];
  uint4 ps[4], pd[4];
  float4 at[4];
  int eidr[4];

  auto load_pk = [&](int t) {
#pragma unroll
    for (int it = 0; it < 4; it++) {
      int e = min(t * 64 + it * 16 + egrp, E - 1);
      pk[it] = csr2[e];
    }
  };
  auto issue_gather = [&](int t) {
#pragma unroll
    for (int it = 0; it < 4; it++) {
      unsigned long long v =
          ((unsigned long long)pk[it].y << 32) | pk[it].x;
      int s = (int)(v & NMASK);
      int d = (int)((v >> 17) & NMASK);
      eidr[it] = (int)(v >> 34);
      ps[it] = *(const uint4*)(Pcatb + (size_t)s * 256 + ac16 * 8);
      pd[it] = *(const uint4*)(Pcatb + (size_t)d * 256 + 128 + ac16 * 8);
      int e = min(t * 64 + it * 16 + egrp, E - 1);
      at[it] = attrp[e];
    }
  };

  int t = blockIdx.x;
  if (t < tiles) {
    load_pk(t);
    issue_gather(t);
    if (t + S < tiles) load_pk(t + S);
  }
  int buf = 0;
  for (; t < tiles; t += S) {
    u16* sv = sV[buf];
    // ---- phase A: consume prefetched regs -> sV[buf]
#pragma unroll
    for (int it = 0; it < 4; it++) {
      int e = it * 16 + egrp;
      uint4 psu = ps[it], pdu = pd[it];
      float4 a4 = at[it];
      unsigned pu[4] = {psu.x, psu.y, psu.z, psu.w};
      unsigned du[4] = {pdu.x, pdu.y, pdu.z, pdu.w};
      uint4 ov;
      unsigned* op = (unsigned*)&ov;
#pragma unroll
      for (int p2 = 0; p2 < 4; p2++) {
        int t0 = p2 * 2, t1 = t0 + 1;
        float f0 = bflo(pu[p2]) + bflo(du[p2]) + a4.x * wa[0][t0] +
                   a4.y * wa[1][t0] + a4.z * wa[2][t0] + a4.w * wa[3][t0];
        float f1 = bfhi(pu[p2]) + bfhi(du[p2]) + a4.x * wa[0][t1] +
                   a4.y * wa[1][t1] + a4.z * wa[2][t1] + a4.w * wa[3][t1];
        op[p2] = pack2bf(fmaxf(f0, 0.0f), fmaxf(f1, 0.0f));
      }
      *(uint4*)(sv + e * 136 + ac16 * 8) = ov;
      if (ac16 == 0) *(unsigned*)(sv + e * 136 + 128) = (unsigned)eidr[it];
    }
    // ---- prefetch tile t+S (overlaps barrier + phase B)
    if (t + S < tiles) {
      issue_gather(t + S);
      if (t + 2 * S < tiles) load_pk(t + 2 * S);
    }
    __syncthreads();
    // ---- phase B: MFMA from LDS
    f32x4 acc[4];
#pragma unroll
    for (int nt = 0; nt < 4; nt++) acc[nt] = (f32x4){0.f, 0.f, 0.f, 0.f};
    const u16* vp = sv + (w * 16 + c16) * 136 + quad * 8;
#pragma unroll
    for (int kt = 0; kt < 4; kt++) {
      bf16x8 av = *(const bf16x8*)(vp + kt * 32);
#pragma unroll
      for (int nt = 0; nt < 4; nt++) {
        bf16x8 bv = *(const bf16x8*)(sW2 + ((kt * 4 + nt) * 64 + l) * 8);
        acc[nt] = __builtin_amdgcn_mfma_f32_16x16x32_bf16(av, bv, acc[nt], 0, 0, 0);
      }
    }
#pragma unroll
    for (int r = 0; r < 4; r++) {
      float p = 0.0f;
#pragma unroll
      for (int nt = 0; nt < 4; nt++)
        p += fmaxf(acc[nt][r] + be2[nt], 0.0f) * w3v[nt];
      p += __shfl_xor(p, 1, 64);
      p += __shfl_xor(p, 2, 64);
      p += __shfl_xor(p, 4, 64);
      p += __shfl_xor(p, 8, 64);
      if (c16 == 0) {
        int eloc = w * 16 + quad * 4 + r;
        if (t * 64 + eloc < E) {
          unsigned eid = *(const unsigned*)(sv + eloc * 136 + 128);
          out[eid] = p + b3;
        }
      }
    }
    buf ^= 1;
  }
}

extern "C" void kernel_launch(void* const* d_in, const int* in_sizes, int n_in,
                              void* d_out, int out_size, void* d_ws,
                              size_t ws_size, hipStream_t stream) {
  const float* x        = (const float*)d_in[0];
  const int*   ei       = (const int*)d_in[1];
  const float* attr     = (const float*)d_in[2];
  const float* w1_root  = (const float*)d_in[3];
  const float* w1_neigh = (const float*)d_in[4];
  const float* b1       = (const float*)d_in[5];
  const float* w2_root  = (const float*)d_in[6];
  const float* w2_neigh = (const float*)d_in[7];
  const float* b2       = (const float*)d_in[8];
  const float* w_e1     = (const float*)d_in[9];
  const float* b_e1     = (const float*)d_in[10];
  const float* w_e2     = (const float*)d_in[11];
  const float* b_e2     = (const float*)d_in[12];
  const float* w_e3     = (const float*)d_in[13];
  const float* b_e3     = (const float*)d_in[14];
  float* out = (float*)d_out;

  int N = in_sizes[0] / 6;
  int E = in_sizes[2] / 4;
  int NBLK = (N + 255) / 256;

  int* wsi = (int*)d_ws;
  int*    rowptr  = wsi;                        // [N+1]
  int*    cursor  = wsi + 100004;               // [N]
  int*    partial = wsi + 200004;               // [512]
  uint2*  csr2    = (uint2*)(wsi + 200520);     // [E] x 8B
  float*  mean1   = (float*)(wsi + 3400520);    // [N,6]
  u16*    cat2b   = (u16*)(wsi + 4000520);      // [N,256] bf16
  u16*    h2b     = (u16*)(wsi + 16800520);     // [N,128] bf16
  u16*    B2f     = (u16*)(wsi + 23200520);     // 32768
  u16*    WSDf    = (u16*)(wsi + 23216904);     // 32768
  u16*    W2f     = (u16*)(wsi + 23233288);     // 8192
  float*  pbias   = (float*)(wsi + 23237384);   // 256
  float4* attrp   = (float4*)(wsi + 23237640);  // [E] x 16B

  hipMemsetAsync(cursor, 0, (size_t)N * sizeof(int), stream);

  pack_weights<<<289, 256, 0, stream>>>(w2_root, w2_neigh, w_e1, w_e2, b_e1,
                                        B2f, WSDf, W2f, pbias);

  // CSR build (by dst)
  hist_kernel<<<(E + 255) / 256, 256, 0, stream>>>(ei, cursor, E);
  scan_block_sums<<<NBLK, 256, 0, stream>>>(cursor, partial, N);
  scan_partials<<<1, 512, 0, stream>>>(partial, rowptr, NBLK, E, N);
  scan_final<<<NBLK, 256, 0, stream>>>(partial, cursor, rowptr, N);
  scatter_csr<<<(E + 255) / 256, 256, 0, stream>>>(ei, cursor, csr2, E);
  permute_attr<<<(E + 255) / 256, 256, 0, stream>>>(attr, csr2, attrp, E);

  // layer 1
  agg1_kernel<<<(N + 3) / 4, 256, 0, stream>>>(x, rowptr, csr2, mean1, N);
  dense1_kernel<<<N, 128, 0, stream>>>(x, mean1, w1_root, w1_neigh, b1, cat2b, N);

  // layer 2 aggregation (wave-parallel bf16 gather)
  agg2_kernel<<<(N + 3) / 4, 256, 0, stream>>>(cat2b, cat2b, rowptr, csr2, N);

  int gblocks = (N + 63) / 64;
  // h2 = relu([h1|mean2] @ [w2_root;w2_neigh] + b2)
  mfma_gemm<8, 8, true><<<gblocks, 256, 0, stream>>>(cat2b, 256, B2f, b2, h2b,
                                                     128, N);
  // Pcat = h2 @ [Ws|Wd] + [0|b_e1]
  mfma_gemm<4, 16, false><<<gblocks, 256, 0, stream>>>(h2b, 128, WSDf, pbias,
                                                       cat2b, 256, N);

  // pipelined fused edge MLP
  edge_mfma_kernel<<<1024, 256, 0, stream>>>(cat2b, csr2, attrp, w_e1, W2f,
                                             b_e2, w_e3, b_e3, out, E);
}

// Round 5
// 612.021 us; speedup vs baseline: 4.1718x; 1.0745x over previous
//
#include <hip/hip_runtime.h>
#include <hip/hip_bf16.h>
#include <stdint.h>

// ---------------------------------------------------------------------------
// UVSeamGNN R5: packed-fp32 (v_pk_*) phase A in edge kernel (was VALU-bound:
// VALUBusy 59%, MfmaUtil 6%); depth-2 pipelined + packed agg2; attr permute
// fused into scatter_csr.
// Workspace (4B words), N=100000, E=1600000:
//   rowptr [N+1]      @ 0
//   cursor [N]        @ 100004
//   partial[512]      @ 200004
//   csr2   [E]x8B     @ 200520   (src | dst<<17 | eid<<34)
//   mean1  [N*6] f32  @ 3400520
//   cat2b  [N][256]b  @ 4000520  (cols 0..127: h1 then Ps; 128..255: mean2 then Pd+b1)
//   h2b    [N][128]b  @ 16800520
//   B2f    [32768]u16 @ 23200520 (frag-packed [w2_root;w2_neigh], KT8 NT8)
//   WSDf   [32768]u16 @ 23216904 (frag-packed [Ws|Wd], KT4 NT16)
//   W2f    [8192]u16  @ 23233288 (frag-packed w_e2, KT4 NT4)
//   pbias  [256] f32  @ 23237384 (0..127: 0, 128..255: b_e1)
//   attrp  [E*4] f32  @ 23237640 (attr permuted to CSR slot order)
// total ~118.5 MB
// ---------------------------------------------------------------------------

typedef unsigned short u16;
typedef short bf16x8 __attribute__((ext_vector_type(8)));
typedef float f32x4 __attribute__((ext_vector_type(4)));
typedef float f32x2 __attribute__((ext_vector_type(2)));

#define NMASK 0x1FFFF

__device__ __forceinline__ u16 f2b(float f) {
  unsigned u = __builtin_bit_cast(unsigned, f);
  u = u + 0x7fffu + ((u >> 16) & 1u);
  return (u16)(u >> 16);
}
__device__ __forceinline__ float bflo(unsigned u) {
  return __builtin_bit_cast(float, u << 16);
}
__device__ __forceinline__ float bfhi(unsigned u) {
  return __builtin_bit_cast(float, u & 0xffff0000u);
}
__device__ __forceinline__ f32x2 unpk2(unsigned u) {
  return (f32x2){bflo(u), bfhi(u)};
}
__device__ __forceinline__ unsigned pack2bf(float a, float b) {
  unsigned ua = __builtin_bit_cast(unsigned, a);
  unsigned ub = __builtin_bit_cast(unsigned, b);
  ua = ua + 0x7fffu + ((ua >> 16) & 1u);
  ub = ub + 0x7fffu + ((ub >> 16) & 1u);
  return (ua >> 16) | (ub & 0xffff0000u);
}

// ---- CSR build ----
__global__ void hist_kernel(const int* __restrict__ ei, int* __restrict__ cnt,
                            int E) {
  int e = blockIdx.x * blockDim.x + threadIdx.x;
  if (e < E) atomicAdd(&cnt[ei[E + e]], 1);
}

__global__ void scan_block_sums(const int* __restrict__ cnt,
                                int* __restrict__ partial, int N) {
  __shared__ int red[256];
  int t = threadIdx.x;
  int n = blockIdx.x * 256 + t;
  red[t] = (n < N) ? cnt[n] : 0;
  __syncthreads();
  for (int off = 128; off; off >>= 1) {
    if (t < off) red[t] += red[t + off];
    __syncthreads();
  }
  if (t == 0) partial[blockIdx.x] = red[0];
}

__global__ void scan_partials(int* __restrict__ partial,
                              int* __restrict__ rowptr, int NBLK, int E,
                              int N) {
  __shared__ int sc[512];
  int t = threadIdx.x;
  int v = (t < NBLK) ? partial[t] : 0;
  sc[t] = v;
  __syncthreads();
  for (int off = 1; off < 512; off <<= 1) {
    int a = (t >= off) ? sc[t - off] : 0;
    __syncthreads();
    sc[t] += a;
    __syncthreads();
  }
  if (t < NBLK) partial[t] = sc[t] - v;  // exclusive
  if (t == 0) rowptr[N] = E;
}

__global__ void scan_final(const int* __restrict__ partial,
                           int* __restrict__ cursor, int* __restrict__ rowptr,
                           int N) {
  __shared__ int sc[256];
  int t = threadIdx.x;
  int n = blockIdx.x * 256 + t;
  int v = (n < N) ? cursor[n] : 0;
  sc[t] = v;
  __syncthreads();
  for (int off = 1; off < 256; off <<= 1) {
    int a = (t >= off) ? sc[t - off] : 0;
    __syncthreads();
    sc[t] += a;
    __syncthreads();
  }
  int excl = partial[blockIdx.x] + sc[t] - v;
  if (n < N) {
    rowptr[n] = excl;
    cursor[n] = excl;
  }
}

// scatter CSR entry + permuted attr in one pass (attr read is coalesced here)
__global__ void scatter_csr(const int* __restrict__ ei,
                            const float* __restrict__ attr,
                            int* __restrict__ cursor, uint2* __restrict__ csr2,
                            float4* __restrict__ attrp, int E) {
  int e = blockIdx.x * blockDim.x + threadIdx.x;
  if (e >= E) return;
  int s = ei[e];
  int d = ei[E + e];
  float4 a4 = *(const float4*)(attr + (size_t)e * 4);
  int pos = atomicAdd(&cursor[d], 1);
  unsigned long long v = (unsigned long long)(unsigned)s |
                         ((unsigned long long)(unsigned)d << 17) |
                         ((unsigned long long)(unsigned)e << 34);
  csr2[pos] = make_uint2((unsigned)v, (unsigned)(v >> 32));
  attrp[pos] = a4;
}

// ---- pack weights into bf16 MFMA B-fragment layouts ----
__global__ void pack_weights(const float* __restrict__ w2_root,
                             const float* __restrict__ w2_neigh,
                             const float* __restrict__ w_e1,
                             const float* __restrict__ w_e2,
                             const float* __restrict__ b_e1,
                             u16* __restrict__ B2f, u16* __restrict__ WSDf,
                             u16* __restrict__ W2f, float* __restrict__ pbias) {
  int t = blockIdx.x * 256 + threadIdx.x;
  if (t < 32768) {  // B2f: KT=8, NT=8 over [w2_root; w2_neigh] (K=256, N=128)
    int j = t & 7, lane = (t >> 3) & 63, nt = (t >> 9) & 7, kt = t >> 12;
    int k = kt * 32 + (lane >> 4) * 8 + j;
    int n = nt * 16 + (lane & 15);
    float v = (k < 128) ? w2_root[k * 128 + n] : w2_neigh[(k - 128) * 128 + n];
    B2f[t] = f2b(v);
  } else if (t < 65536) {  // WSDf: KT=4, NT=16 over [Ws | Wd] (K=128, N=256)
    int t2 = t - 32768;
    int j = t2 & 7, lane = (t2 >> 3) & 63, nt = (t2 >> 9) & 15, kt = t2 >> 13;
    int k = kt * 32 + (lane >> 4) * 8 + j;
    int n = nt * 16 + (lane & 15);
    float v = (n < 128) ? w_e1[k * 128 + n] : w_e1[(128 + k) * 128 + (n - 128)];
    WSDf[t2] = f2b(v);
  } else if (t < 73728) {  // W2f: KT=4, NT=4 over w_e2 (K=128, N=64)
    int t2 = t - 65536;
    int j = t2 & 7, lane = (t2 >> 3) & 63, nt = (t2 >> 9) & 3, kt = t2 >> 11;
    int k = kt * 32 + (lane >> 4) * 8 + j;
    int n = nt * 16 + (lane & 15);
    W2f[t2] = f2b(w_e2[k * 64 + n]);
  } else if (t < 73984) {  // pbias
    int n = t - 73728;
    pbias[n] = (n < 128) ? 0.0f : b_e1[n - 128];
  }
}

// ---- layer-1 mean aggregation: wave per node, 8 rows x 8 lanes ----
__global__ __launch_bounds__(256) void agg1_kernel(
    const float* __restrict__ x, const int* __restrict__ rowptr,
    const uint2* __restrict__ csr2, float* __restrict__ mean1, int N) {
  int n = blockIdx.x * 4 + (threadIdx.x >> 6);
  if (n >= N) return;
  int lane = threadIdx.x & 63;
  int g = lane >> 3;  // row group 0..7
  int c = lane & 7;   // col 0..7 (0..5 valid)
  int beg = rowptr[n], end = rowptr[n + 1];
  float a = 0.0f;
  if (c < 6) {
    for (int i = beg + g; i < end; i += 8) {
      int s = (int)(csr2[i].x & NMASK);
      a += x[(size_t)s * 6 + c];
    }
  }
  a += __shfl_xor(a, 8, 64);
  a += __shfl_xor(a, 16, 64);
  a += __shfl_xor(a, 32, 64);
  if (g == 0 && c < 6)
    mean1[(size_t)n * 6 + c] = a / (float)max(end - beg, 1);
}

// ---- dense layer 1 -> h1 bf16 into cat2b cols 0..127 ----
__global__ void dense1_kernel(const float* __restrict__ x,
                              const float* __restrict__ mean1,
                              const float* __restrict__ w_root,
                              const float* __restrict__ w_neigh,
                              const float* __restrict__ b,
                              u16* __restrict__ cat2b, int N) {
  int n = blockIdx.x;
  int m = threadIdx.x;
  if (n >= N) return;
  float s = b[m];
#pragma unroll
  for (int j = 0; j < 6; j++) {
    s += x[(size_t)n * 6 + j] * w_root[j * 128 + m] +
         mean1[(size_t)n * 6 + j] * w_neigh[j * 128 + m];
  }
  cat2b[(size_t)n * 256 + m] = f2b(fmaxf(s, 0.0f));
}

// ---- layer-2 mean aggregation: wave/node, 4 rows x 16 lanes, depth-2 pipe --
__global__ __launch_bounds__(256) void agg2_kernel(
    const u16* __restrict__ cat2b, u16* __restrict__ cat2w,
    const int* __restrict__ rowptr, const uint2* __restrict__ csr2, int N) {
  int n = blockIdx.x * 4 + (threadIdx.x >> 6);
  if (n >= N) return;
  int lane = threadIdx.x & 63;
  int g = lane >> 4;  // row group 0..3
  int c = lane & 15;  // col chunk (8 bf16)
  int beg = rowptr[n], end = rowptr[n + 1];
  f32x2 acc2[4];
#pragma unroll
  for (int j = 0; j < 4; j++) acc2[j] = (f32x2){0.f, 0.f};

  int i = beg + g;
  uint4 u0, u1;
  bool h0 = i < end, h1 = (i + 4) < end;
  if (h0)
    u0 = *(const uint4*)(cat2b + (size_t)(csr2[i].x & NMASK) * 256 + c * 8);
  if (h1)
    u1 = *(const uint4*)(cat2b + (size_t)(csr2[i + 4].x & NMASK) * 256 + c * 8);
  while (h0) {
    uint4 uc = u0;
    i += 4;
    h0 = h1;
    u0 = u1;
    h1 = (i + 4) < end;
    if (h1)
      u1 = *(const uint4*)(cat2b + (size_t)(csr2[i + 4].x & NMASK) * 256 + c * 8);
    acc2[0] += unpk2(uc.x);
    acc2[1] += unpk2(uc.y);
    acc2[2] += unpk2(uc.z);
    acc2[3] += unpk2(uc.w);
  }
#pragma unroll
  for (int j = 0; j < 4; j++) {
    acc2[j].x += __shfl_xor(acc2[j].x, 16, 64);
    acc2[j].y += __shfl_xor(acc2[j].y, 16, 64);
    acc2[j].x += __shfl_xor(acc2[j].x, 32, 64);
    acc2[j].y += __shfl_xor(acc2[j].y, 32, 64);
  }
  if (g == 0) {
    float inv = 1.0f / (float)max(end - beg, 1);
    uint4 ov;
    ov.x = pack2bf(acc2[0].x * inv, acc2[0].y * inv);
    ov.y = pack2bf(acc2[1].x * inv, acc2[1].y * inv);
    ov.z = pack2bf(acc2[2].x * inv, acc2[2].y * inv);
    ov.w = pack2bf(acc2[3].x * inv, acc2[3].y * inv);
    *(uint4*)(cat2w + (size_t)n * 256 + 128 + c * 8) = ov;
  }
}

// ---- bf16 MFMA GEMM: C[M,NT*16] = op(A[M,KT*32] @ Bfrag + bias) ----
template <int KT, int NT, bool RELU>
__global__ __launch_bounds__(256) void mfma_gemm(
    const u16* __restrict__ A, int lda, const u16* __restrict__ Bf,
    const float* __restrict__ bias, u16* __restrict__ C, int ldc, int M) {
  __shared__ u16 sB[KT * NT * 512];
  int tid = threadIdx.x;
  for (int i = tid; i < KT * NT * 64; i += 256)
    ((uint4*)sB)[i] = ((const uint4*)Bf)[i];
  int w = tid >> 6, l = tid & 63;
  int quad = l >> 4, col16 = l & 15;
  int rowA = blockIdx.x * 64 + w * 16 + col16;
  bool rv = rowA < M;
  const u16* ap = A + (size_t)rowA * lda + quad * 8;
  f32x4 acc[NT];
#pragma unroll
  for (int nt = 0; nt < NT; nt++) acc[nt] = (f32x4){0.f, 0.f, 0.f, 0.f};
  __syncthreads();
#pragma unroll
  for (int kt = 0; kt < KT; kt++) {
    bf16x8 av = {};
    if (rv) av = *(const bf16x8*)(ap + kt * 32);
#pragma unroll
    for (int nt = 0; nt < NT; nt++) {
      bf16x8 bv = *(const bf16x8*)(sB + ((kt * NT + nt) * 64 + l) * 8);
      acc[nt] = __builtin_amdgcn_mfma_f32_16x16x32_bf16(av, bv, acc[nt], 0, 0, 0);
    }
  }
  int rowbase = blockIdx.x * 64 + w * 16 + quad * 4;
#pragma unroll
  for (int r = 0; r < 4; r++) {
    int row = rowbase + r;
    if (row < M) {
#pragma unroll
      for (int nt = 0; nt < NT; nt++) {
        float v = acc[nt][r] + bias[nt * 16 + col16];
        if (RELU) v = fmaxf(v, 0.0f);
        C[(size_t)row * ldc + nt * 16 + col16] = f2b(v);
      }
    }
  }
}

// ---- pipelined edge MLP, packed-fp32 phase A ----
__global__ __launch_bounds__(256) void edge_mfma_kernel(
    const u16* __restrict__ Pcatb, const uint2* __restrict__ csr2,
    const float4* __restrict__ attrp, const float* __restrict__ w_e1,
    const u16* __restrict__ W2f, const float* __restrict__ b_e2,
    const float* __restrict__ w_e3, const float* __restrict__ b_e3,
    float* __restrict__ out, int E) {
  __shared__ u16 sV[2][64 * 136];  // cols 0..127 = V, u16 slot 128.. = eid
  __shared__ u16 sW2[8192];

  int tid = threadIdx.x;
  int w = tid >> 6, l = tid & 63, quad = l >> 4, c16 = l & 15;
  int egrp = tid >> 4, ac16 = tid & 15;

  for (int i = tid; i < 1024; i += 256)
    ((uint4*)sW2)[i] = ((const uint4*)W2f)[i];

  // wa2[j][p2]: rows j=0..3 of Wa, column pair p2 for this thread's 8 cols
  f32x2 wa2[4][4];
#pragma unroll
  for (int j = 0; j < 4; j++) {
    float4 w0 = *(const float4*)(w_e1 + (256 + j) * 128 + ac16 * 8);
    float4 w1 = *(const float4*)(w_e1 + (256 + j) * 128 + ac16 * 8 + 4);
    wa2[j][0] = (f32x2){w0.x, w0.y};
    wa2[j][1] = (f32x2){w0.z, w0.w};
    wa2[j][2] = (f32x2){w1.x, w1.y};
    wa2[j][3] = (f32x2){w1.z, w1.w};
  }
  float w3v[4], be2[4];
#pragma unroll
  for (int nt = 0; nt < 4; nt++) {
    w3v[nt] = w_e3[nt * 16 + c16];
    be2[nt] = b_e2[nt * 16 + c16];
  }
  float b3 = b_e3[0];

  int tiles = (E + 63) >> 6;
  int S = gridDim.x;

  uint2 pk[4];
  uint4 ps[4], pd[4];
  float4 at[4];
  int eidr[4];

  auto load_pk = [&](int t) {
#pragma unroll
    for (int it = 0; it < 4; it++) {
      int e = min(t * 64 + it * 16 + egrp, E - 1);
      pk[it] = csr2[e];
    }
  };
  auto issue_gather = [&](int t) {
#pragma unroll
    for (int it = 0; it < 4; it++) {
      unsigned long long v = ((unsigned long long)pk[it].y << 32) | pk[it].x;
      int s = (int)(v & NMASK);
      int d = (int)((v >> 17) & NMASK);
      eidr[it] = (int)(v >> 34);
      ps[it] = *(const uint4*)(Pcatb + (size_t)s * 256 + ac16 * 8);
      pd[it] = *(const uint4*)(Pcatb + (size_t)d * 256 + 128 + ac16 * 8);
      int e = min(t * 64 + it * 16 + egrp, E - 1);
      at[it] = attrp[e];
    }
  };

  int t = blockIdx.x;
  if (t < tiles) {
    load_pk(t);
    issue_gather(t);
    if (t + S < tiles) load_pk(t + S);
  }
  int buf = 0;
  for (; t < tiles; t += S) {
    u16* sv = sV[buf];
    // ---- phase A (packed fp32): V = relu(Ps + Pd' + attr@Wa)
#pragma unroll
    for (int it = 0; it < 4; it++) {
      int e = it * 16 + egrp;
      uint4 psu = ps[it], pdu = pd[it];
      float4 a4 = at[it];
      unsigned pu[4] = {psu.x, psu.y, psu.z, psu.w};
      unsigned du[4] = {pdu.x, pdu.y, pdu.z, pdu.w};
      uint4 ov;
      unsigned* op = (unsigned*)&ov;
#pragma unroll
      for (int p2 = 0; p2 < 4; p2++) {
        f32x2 f = unpk2(pu[p2]) + unpk2(du[p2]);
        f += a4.x * wa2[0][p2];
        f += a4.y * wa2[1][p2];
        f += a4.z * wa2[2][p2];
        f += a4.w * wa2[3][p2];
        f = __builtin_elementwise_max(f, (f32x2){0.f, 0.f});
        op[p2] = pack2bf(f.x, f.y);
      }
      *(uint4*)(sv + e * 136 + ac16 * 8) = ov;
      if (ac16 == 0) *(unsigned*)(sv + e * 136 + 128) = (unsigned)eidr[it];
    }
    // ---- prefetch tile t+S (overlaps barrier + phase B)
    if (t + S < tiles) {
      issue_gather(t + S);
      if (t + 2 * S < tiles) load_pk(t + 2 * S);
    }
    __syncthreads();
    // ---- phase B: MFMA from LDS
    f32x4 acc[4];
#pragma unroll
    for (int nt = 0; nt < 4; nt++) acc[nt] = (f32x4){0.f, 0.f, 0.f, 0.f};
    const u16* vp = sV[buf] + (w * 16 + c16) * 136 + quad * 8;
#pragma unroll
    for (int kt = 0; kt < 4; kt++) {
      bf16x8 av = *(const bf16x8*)(vp + kt * 32);
#pragma unroll
      for (int nt = 0; nt < 4; nt++) {
        bf16x8 bv = *(const bf16x8*)(sW2 + ((kt * 4 + nt) * 64 + l) * 8);
        acc[nt] = __builtin_amdgcn_mfma_f32_16x16x32_bf16(av, bv, acc[nt], 0, 0, 0);
      }
    }
#pragma unroll
    for (int r = 0; r < 4; r++) {
      float p = 0.0f;
#pragma unroll
      for (int nt = 0; nt < 4; nt++)
        p += fmaxf(acc[nt][r] + be2[nt], 0.0f) * w3v[nt];
      p += __shfl_xor(p, 1, 64);
      p += __shfl_xor(p, 2, 64);
      p += __shfl_xor(p, 4, 64);
      p += __shfl_xor(p, 8, 64);
      if (c16 == 0) {
        int eloc = w * 16 + quad * 4 + r;
        if (t * 64 + eloc < E) {
          unsigned eid = *(const unsigned*)(sV[buf] + eloc * 136 + 128);
          out[eid] = p + b3;
        }
      }
    }
    buf ^= 1;
  }
}

extern "C" void kernel_launch(void* const* d_in, const int* in_sizes, int n_in,
                              void* d_out, int out_size, void* d_ws,
                              size_t ws_size, hipStream_t stream) {
  const float* x        = (const float*)d_in[0];
  const int*   ei       = (const int*)d_in[1];
  const float* attr     = (const float*)d_in[2];
  const float* w1_root  = (const float*)d_in[3];
  const float* w1_neigh = (const float*)d_in[4];
  const float* b1       = (const float*)d_in[5];
  const float* w2_root  = (const float*)d_in[6];
  const float* w2_neigh = (const float*)d_in[7];
  const float* b2       = (const float*)d_in[8];
  const float* w_e1     = (const float*)d_in[9];
  const float* b_e1     = (const float*)d_in[10];
  const float* w_e2     = (const float*)d_in[11];
  const float* b_e2     = (const float*)d_in[12];
  const float* w_e3     = (const float*)d_in[13];
  const float* b_e3     = (const float*)d_in[14];
  float* out = (float*)d_out;

  int N = in_sizes[0] / 6;
  int E = in_sizes[2] / 4;
  int NBLK = (N + 255) / 256;

  int* wsi = (int*)d_ws;
  int*    rowptr  = wsi;                        // [N+1]
  int*    cursor  = wsi + 100004;               // [N]
  int*    partial = wsi + 200004;               // [512]
  uint2*  csr2    = (uint2*)(wsi + 200520);     // [E] x 8B
  float*  mean1   = (float*)(wsi + 3400520);    // [N,6]
  u16*    cat2b   = (u16*)(wsi + 4000520);      // [N,256] bf16
  u16*    h2b     = (u16*)(wsi + 16800520);     // [N,128] bf16
  u16*    B2f     = (u16*)(wsi + 23200520);     // 32768
  u16*    WSDf    = (u16*)(wsi + 23216904);     // 32768
  u16*    W2f     = (u16*)(wsi + 23233288);     // 8192
  float*  pbias   = (float*)(wsi + 23237384);   // 256
  float4* attrp   = (float4*)(wsi + 23237640);  // [E] x 16B

  hipMemsetAsync(cursor, 0, (size_t)N * sizeof(int), stream);

  pack_weights<<<289, 256, 0, stream>>>(w2_root, w2_neigh, w_e1, w_e2, b_e1,
                                        B2f, WSDf, W2f, pbias);

  // CSR build (by dst), attr permuted in the same pass
  hist_kernel<<<(E + 255) / 256, 256, 0, stream>>>(ei, cursor, E);
  scan_block_sums<<<NBLK, 256, 0, stream>>>(cursor, partial, N);
  scan_partials<<<1, 512, 0, stream>>>(partial, rowptr, NBLK, E, N);
  scan_final<<<NBLK, 256, 0, stream>>>(partial, cursor, rowptr, N);
  scatter_csr<<<(E + 255) / 256, 256, 0, stream>>>(ei, attr, cursor, csr2,
                                                   attrp, E);

  // layer 1
  agg1_kernel<<<(N + 3) / 4, 256, 0, stream>>>(x, rowptr, csr2, mean1, N);
  dense1_kernel<<<N, 128, 0, stream>>>(x, mean1, w1_root, w1_neigh, b1, cat2b, N);

  // layer 2 aggregation (pipelined bf16 gather)
  agg2_kernel<<<(N + 3) / 4, 256, 0, stream>>>(cat2b, cat2b, rowptr, csr2, N);

  int gblocks = (N + 63) / 64;
  // h2 = relu([h1|mean2] @ [w2_root;w2_neigh] + b2)
  mfma_gemm<8, 8, true><<<gblocks, 256, 0, stream>>>(cat2b, 256, B2f, b2, h2b,
                                                     128, N);
  // Pcat = h2 @ [Ws|Wd] + [0|b_e1]
  mfma_gemm<4, 16, false><<<gblocks, 256, 0, stream>>>(h2b, 128, WSDf, pbias,
                                                       cat2b, 256, N);

  // pipelined fused edge MLP
  edge_mfma_kernel<<<1024, 256, 0, stream>>>(cat2b, csr2, attrp, w_e1, W2f,
                                             b_e2, w_e3, b_e3, out, E);
}

// Round 7
// 604.039 us; speedup vs baseline: 4.2269x; 1.0132x over previous
//
#include <hip/hip_runtime.h>
#include <hip/hip_bf16.h>
#include <stdint.h>

// ---------------------------------------------------------------------------
// UVSeamGNN R6b: R6 with packrn compile fix (memcpy instead of bit_cast on
// __hip_bfloat162). Edge kernel single-buffer LDS (33.8KB -> 4 blocks/CU);
// deep-prefetch agg2 (6 gathers in flight/lane); agg1 4-deep; dense1
// LDS-staged; hw packed bf16 cvt.
// Workspace (4B words), N=100000, E=1600000:
//   rowptr [N+1]      @ 0
//   cursor [N]        @ 100004
//   partial[512]      @ 200004
//   csr2   [E]x8B     @ 200520   (src | dst<<17 | eid<<34)
//   mean1  [N*6] f32  @ 3400520
//   cat2b  [N][256]b  @ 4000520  (cols 0..127: h1 then Ps; 128..255: mean2 then Pd+b1)
//   h2b    [N][128]b  @ 16800520
//   B2f    [32768]u16 @ 23200520 (frag-packed [w2_root;w2_neigh], KT8 NT8)
//   WSDf   [32768]u16 @ 23216904 (frag-packed [Ws|Wd], KT4 NT16)
//   W2f    [8192]u16  @ 23233288 (frag-packed w_e2, KT4 NT4)
//   pbias  [256] f32  @ 23237384 (0..127: 0, 128..255: b_e1)
//   attrp  [E*4] f32  @ 23237640 (attr permuted to CSR slot order)
// total ~118.5 MB
// ---------------------------------------------------------------------------

typedef unsigned short u16;
typedef short bf16x8 __attribute__((ext_vector_type(8)));
typedef float f32x4 __attribute__((ext_vector_type(4)));
typedef float f32x2 __attribute__((ext_vector_type(2)));

#define NMASK 0x1FFFF

__device__ __forceinline__ u16 f2b(float f) {
  unsigned u = __builtin_bit_cast(unsigned, f);
  u = u + 0x7fffu + ((u >> 16) & 1u);
  return (u16)(u >> 16);
}
__device__ __forceinline__ float bflo(unsigned u) {
  return __builtin_bit_cast(float, u << 16);
}
__device__ __forceinline__ float bfhi(unsigned u) {
  return __builtin_bit_cast(float, u & 0xffff0000u);
}
__device__ __forceinline__ f32x2 unpk2(unsigned u) {
  return (f32x2){bflo(u), bfhi(u)};
}
__device__ __forceinline__ unsigned pack2bf(float a, float b) {
  unsigned ua = __builtin_bit_cast(unsigned, a);
  unsigned ub = __builtin_bit_cast(unsigned, b);
  ua = ua + 0x7fffu + ((ua >> 16) & 1u);
  ub = ub + 0x7fffu + ((ub >> 16) & 1u);
  return (ua >> 16) | (ub & 0xffff0000u);
}
__device__ __forceinline__ unsigned packrn(f32x2 f) {
  __hip_bfloat162 h = __float22bfloat162_rn(make_float2(f.x, f.y));
  unsigned r;
  __builtin_memcpy(&r, &h, 4);
  return r;
}

// ---- CSR build ----
__global__ void hist_kernel(const int* __restrict__ ei, int* __restrict__ cnt,
                            int E) {
  int e = blockIdx.x * blockDim.x + threadIdx.x;
  if (e < E) atomicAdd(&cnt[ei[E + e]], 1);
}

__global__ void scan_block_sums(const int* __restrict__ cnt,
                                int* __restrict__ partial, int N) {
  __shared__ int red[256];
  int t = threadIdx.x;
  int n = blockIdx.x * 256 + t;
  red[t] = (n < N) ? cnt[n] : 0;
  __syncthreads();
  for (int off = 128; off; off >>= 1) {
    if (t < off) red[t] += red[t + off];
    __syncthreads();
  }
  if (t == 0) partial[blockIdx.x] = red[0];
}

__global__ void scan_partials(int* __restrict__ partial,
                              int* __restrict__ rowptr, int NBLK, int E,
                              int N) {
  __shared__ int sc[512];
  int t = threadIdx.x;
  int v = (t < NBLK) ? partial[t] : 0;
  sc[t] = v;
  __syncthreads();
  for (int off = 1; off < 512; off <<= 1) {
    int a = (t >= off) ? sc[t - off] : 0;
    __syncthreads();
    sc[t] += a;
    __syncthreads();
  }
  if (t < NBLK) partial[t] = sc[t] - v;  // exclusive
  if (t == 0) rowptr[N] = E;
}

__global__ void scan_final(const int* __restrict__ partial,
                           int* __restrict__ cursor, int* __restrict__ rowptr,
                           int N) {
  __shared__ int sc[256];
  int t = threadIdx.x;
  int n = blockIdx.x * 256 + t;
  int v = (n < N) ? cursor[n] : 0;
  sc[t] = v;
  __syncthreads();
  for (int off = 1; off < 256; off <<= 1) {
    int a = (t >= off) ? sc[t - off] : 0;
    __syncthreads();
    sc[t] += a;
    __syncthreads();
  }
  int excl = partial[blockIdx.x] + sc[t] - v;
  if (n < N) {
    rowptr[n] = excl;
    cursor[n] = excl;
  }
}

// scatter CSR entry + permuted attr in one pass (attr read is coalesced here)
__global__ void scatter_csr(const int* __restrict__ ei,
                            const float* __restrict__ attr,
                            int* __restrict__ cursor, uint2* __restrict__ csr2,
                            float4* __restrict__ attrp, int E) {
  int e = blockIdx.x * blockDim.x + threadIdx.x;
  if (e >= E) return;
  int s = ei[e];
  int d = ei[E + e];
  float4 a4 = *(const float4*)(attr + (size_t)e * 4);
  int pos = atomicAdd(&cursor[d], 1);
  unsigned long long v = (unsigned long long)(unsigned)s |
                         ((unsigned long long)(unsigned)d << 17) |
                         ((unsigned long long)(unsigned)e << 34);
  csr2[pos] = make_uint2((unsigned)v, (unsigned)(v >> 32));
  attrp[pos] = a4;
}

// ---- pack weights into bf16 MFMA B-fragment layouts ----
__global__ void pack_weights(const float* __restrict__ w2_root,
                             const float* __restrict__ w2_neigh,
                             const float* __restrict__ w_e1,
                             const float* __restrict__ w_e2,
                             const float* __restrict__ b_e1,
                             u16* __restrict__ B2f, u16* __restrict__ WSDf,
                             u16* __restrict__ W2f, float* __restrict__ pbias) {
  int t = blockIdx.x * 256 + threadIdx.x;
  if (t < 32768) {  // B2f: KT=8, NT=8 over [w2_root; w2_neigh] (K=256, N=128)
    int j = t & 7, lane = (t >> 3) & 63, nt = (t >> 9) & 7, kt = t >> 12;
    int k = kt * 32 + (lane >> 4) * 8 + j;
    int n = nt * 16 + (lane & 15);
    float v = (k < 128) ? w2_root[k * 128 + n] : w2_neigh[(k - 128) * 128 + n];
    B2f[t] = f2b(v);
  } else if (t < 65536) {  // WSDf: KT=4, NT=16 over [Ws | Wd] (K=128, N=256)
    int t2 = t - 32768;
    int j = t2 & 7, lane = (t2 >> 3) & 63, nt = (t2 >> 9) & 15, kt = t2 >> 13;
    int k = kt * 32 + (lane >> 4) * 8 + j;
    int n = nt * 16 + (lane & 15);
    float v = (n < 128) ? w_e1[k * 128 + n] : w_e1[(128 + k) * 128 + (n - 128)];
    WSDf[t2] = f2b(v);
  } else if (t < 73728) {  // W2f: KT=4, NT=4 over w_e2 (K=128, N=64)
    int t2 = t - 65536;
    int j = t2 & 7, lane = (t2 >> 3) & 63, nt = (t2 >> 9) & 3, kt = t2 >> 11;
    int k = kt * 32 + (lane >> 4) * 8 + j;
    int n = nt * 16 + (lane & 15);
    W2f[t2] = f2b(w_e2[k * 64 + n]);
  } else if (t < 73984) {  // pbias
    int n = t - 73728;
    pbias[n] = (n < 128) ? 0.0f : b_e1[n - 128];
  }
}

// ---- layer-1 mean aggregation: wave/node, 8 rows x 8 lanes, 4-deep ----
__global__ __launch_bounds__(256) void agg1_kernel(
    const float* __restrict__ x, const int* __restrict__ rowptr,
    const uint2* __restrict__ csr2, float* __restrict__ mean1, int N) {
  int n = blockIdx.x * 4 + (threadIdx.x >> 6);
  if (n >= N) return;
  int lane = threadIdx.x & 63;
  int g = lane >> 3;  // row group 0..7
  int c = lane & 7;   // col 0..7 (0..5 valid)
  int beg = rowptr[n], end = rowptr[n + 1];
  float a = 0.0f;
  if (c < 6) {
    int idx[4];
#pragma unroll
    for (int j = 0; j < 4; j++) {
      int ii = beg + g + j * 8;
      idx[j] = (ii < end) ? (int)(csr2[ii].x & NMASK) : -1;
    }
    float v[4];
#pragma unroll
    for (int j = 0; j < 4; j++)
      v[j] = x[(size_t)(idx[j] < 0 ? 0 : idx[j]) * 6 + c];
#pragma unroll
    for (int j = 0; j < 4; j++)
      if (idx[j] >= 0) a += v[j];
    for (int ii = beg + g + 32; ii < end; ii += 8) {
      int s = (int)(csr2[ii].x & NMASK);
      a += x[(size_t)s * 6 + c];
    }
  }
  a += __shfl_xor(a, 8, 64);
  a += __shfl_xor(a, 16, 64);
  a += __shfl_xor(a, 32, 64);
  if (g == 0 && c < 6)
    mean1[(size_t)n * 6 + c] = a / (float)max(end - beg, 1);
}

// ---- dense layer 1 -> h1 bf16 into cat2b cols 0..127, LDS-staged ----
__global__ __launch_bounds__(256) void dense1_kernel(
    const float* __restrict__ x, const float* __restrict__ mean1,
    const float* __restrict__ w_root, const float* __restrict__ w_neigh,
    const float* __restrict__ b, u16* __restrict__ cat2b, int N) {
  __shared__ float sxm[384];  // [0:192) x for 32 nodes, [192:384) mean1
  int t = threadIdx.x;
  int col = t & 127;
  int half = t >> 7;
  float wr[6], wn[6];
#pragma unroll
  for (int j = 0; j < 6; j++) {
    wr[j] = w_root[j * 128 + col];
    wn[j] = w_neigh[j * 128 + col];
  }
  float bb = b[col];
  for (int base = blockIdx.x * 32; base < N; base += gridDim.x * 32) {
    int cnt = min(32, N - base) * 6;
    __syncthreads();
    for (int i = t; i < 384; i += 256) {
      if (i < 192)
        sxm[i] = (i < cnt) ? x[(size_t)base * 6 + i] : 0.0f;
      else
        sxm[i] = (i - 192 < cnt) ? mean1[(size_t)base * 6 + (i - 192)] : 0.0f;
    }
    __syncthreads();
#pragma unroll
    for (int sub = 0; sub < 16; sub++) {
      int nl = sub * 2 + half;
      int n = base + nl;
      if (n < N) {
        float s = bb;
#pragma unroll
        for (int j = 0; j < 6; j++)
          s += sxm[nl * 6 + j] * wr[j] + sxm[192 + nl * 6 + j] * wn[j];
        cat2b[(size_t)n * 256 + col] = f2b(fmaxf(s, 0.0f));
      }
    }
  }
}

// ---- layer-2 mean aggregation: wave/node, 4x16 lanes, 6-deep prefetch ----
__global__ __launch_bounds__(256) void agg2_kernel(
    const u16* __restrict__ cat2b, u16* __restrict__ cat2w,
    const int* __restrict__ rowptr, const uint2* __restrict__ csr2, int N) {
  int n = blockIdx.x * 4 + (threadIdx.x >> 6);
  if (n >= N) return;
  int lane = threadIdx.x & 63;
  int g = lane >> 4;  // row group 0..3
  int c = lane & 15;  // col chunk (8 bf16)
  int beg = rowptr[n], end = rowptr[n + 1];
  f32x2 acc2[4];
#pragma unroll
  for (int j = 0; j < 4; j++) acc2[j] = (f32x2){0.f, 0.f};

  const int DEPTH = 6;
  int idx[DEPTH];
#pragma unroll
  for (int j = 0; j < DEPTH; j++) {
    int ii = beg + g + j * 4;
    idx[j] = (ii < end) ? (int)(csr2[ii].x & NMASK) : -1;
  }
  uint4 u[DEPTH];
#pragma unroll
  for (int j = 0; j < DEPTH; j++) {
    int s = idx[j] < 0 ? 0 : idx[j];
    u[j] = *(const uint4*)(cat2b + (size_t)s * 256 + c * 8);
  }
#pragma unroll
  for (int j = 0; j < DEPTH; j++) {
    if (idx[j] >= 0) {
      acc2[0] += unpk2(u[j].x);
      acc2[1] += unpk2(u[j].y);
      acc2[2] += unpk2(u[j].z);
      acc2[3] += unpk2(u[j].w);
    }
  }
  for (int ii = beg + g + DEPTH * 4; ii < end; ii += 4) {
    int s = (int)(csr2[ii].x & NMASK);
    uint4 uu = *(const uint4*)(cat2b + (size_t)s * 256 + c * 8);
    acc2[0] += unpk2(uu.x);
    acc2[1] += unpk2(uu.y);
    acc2[2] += unpk2(uu.z);
    acc2[3] += unpk2(uu.w);
  }
#pragma unroll
  for (int j = 0; j < 4; j++) {
    acc2[j].x += __shfl_xor(acc2[j].x, 16, 64);
    acc2[j].y += __shfl_xor(acc2[j].y, 16, 64);
    acc2[j].x += __shfl_xor(acc2[j].x, 32, 64);
    acc2[j].y += __shfl_xor(acc2[j].y, 32, 64);
  }
  if (g == 0) {
    float inv = 1.0f / (float)max(end - beg, 1);
    uint4 ov;
    ov.x = packrn(acc2[0] * inv);
    ov.y = packrn(acc2[1] * inv);
    ov.z = packrn(acc2[2] * inv);
    ov.w = packrn(acc2[3] * inv);
    *(uint4*)(cat2w + (size_t)n * 256 + 128 + c * 8) = ov;
  }
}

// ---- bf16 MFMA GEMM: C[M,NT*16] = op(A[M,KT*32] @ Bfrag + bias) ----
template <int KT, int NT, bool RELU>
__global__ __launch_bounds__(256) void mfma_gemm(
    const u16* __restrict__ A, int lda, const u16* __restrict__ Bf,
    const float* __restrict__ bias, u16* __restrict__ C, int ldc, int M) {
  __shared__ u16 sB[KT * NT * 512];
  int tid = threadIdx.x;
  for (int i = tid; i < KT * NT * 64; i += 256)
    ((uint4*)sB)[i] = ((const uint4*)Bf)[i];
  int w = tid >> 6, l = tid & 63;
  int quad = l >> 4, col16 = l & 15;
  int rowA = blockIdx.x * 64 + w * 16 + col16;
  bool rv = rowA < M;
  const u16* ap = A + (size_t)rowA * lda + quad * 8;
  f32x4 acc[NT];
#pragma unroll
  for (int nt = 0; nt < NT; nt++) acc[nt] = (f32x4){0.f, 0.f, 0.f, 0.f};
  __syncthreads();
#pragma unroll
  for (int kt = 0; kt < KT; kt++) {
    bf16x8 av = {};
    if (rv) av = *(const bf16x8*)(ap + kt * 32);
#pragma unroll
    for (int nt = 0; nt < NT; nt++) {
      bf16x8 bv = *(const bf16x8*)(sB + ((kt * NT + nt) * 64 + l) * 8);
      acc[nt] = __builtin_amdgcn_mfma_f32_16x16x32_bf16(av, bv, acc[nt], 0, 0, 0);
    }
  }
  int rowbase = blockIdx.x * 64 + w * 16 + quad * 4;
#pragma unroll
  for (int r = 0; r < 4; r++) {
    int row = rowbase + r;
    if (row < M) {
#pragma unroll
      for (int nt = 0; nt < NT; nt++) {
        float v = acc[nt][r] + bias[nt * 16 + col16];
        if (RELU) v = fmaxf(v, 0.0f);
        C[(size_t)row * ldc + nt * 16 + col16] = f2b(v);
      }
    }
  }
}

// ---- pipelined edge MLP, single-buffer LDS (4 blocks/CU) ----
__global__ __launch_bounds__(256) void edge_mfma_kernel(
    const u16* __restrict__ Pcatb, const uint2* __restrict__ csr2,
    const float4* __restrict__ attrp, const float* __restrict__ w_e1,
    const u16* __restrict__ W2f, const float* __restrict__ b_e2,
    const float* __restrict__ w_e3, const float* __restrict__ b_e3,
    float* __restrict__ out, int E) {
  __shared__ u16 sV[64 * 136];  // cols 0..127 = V, u16 slot 128.. = eid
  __shared__ u16 sW2[8192];

  int tid = threadIdx.x;
  int w = tid >> 6, l = tid & 63, quad = l >> 4, c16 = l & 15;
  int egrp = tid >> 4, ac16 = tid & 15;

  for (int i = tid; i < 1024; i += 256)
    ((uint4*)sW2)[i] = ((const uint4*)W2f)[i];

  // wa2[j][p2]: rows j=0..3 of Wa, column pair p2 for this thread's 8 cols
  f32x2 wa2[4][4];
#pragma unroll
  for (int j = 0; j < 4; j++) {
    float4 w0 = *(const float4*)(w_e1 + (256 + j) * 128 + ac16 * 8);
    float4 w1 = *(const float4*)(w_e1 + (256 + j) * 128 + ac16 * 8 + 4);
    wa2[j][0] = (f32x2){w0.x, w0.y};
    wa2[j][1] = (f32x2){w0.z, w0.w};
    wa2[j][2] = (f32x2){w1.x, w1.y};
    wa2[j][3] = (f32x2){w1.z, w1.w};
  }
  float w3v[4], be2[4];
#pragma unroll
  for (int nt = 0; nt < 4; nt++) {
    w3v[nt] = w_e3[nt * 16 + c16];
    be2[nt] = b_e2[nt * 16 + c16];
  }
  float b3 = b_e3[0];

  int tiles = (E + 63) >> 6;
  int S = gridDim.x;

  uint2 pk[4];
  uint4 ps[4], pd[4];
  float4 at[4];
  int eidr[4];

  auto load_pk = [&](int t) {
#pragma unroll
    for (int it = 0; it < 4; it++) {
      int e = min(t * 64 + it * 16 + egrp, E - 1);
      pk[it] = csr2[e];
    }
  };
  auto issue_gather = [&](int t) {
#pragma unroll
    for (int it = 0; it < 4; it++) {
      unsigned long long v = ((unsigned long long)pk[it].y << 32) | pk[it].x;
      int s = (int)(v & NMASK);
      int d = (int)((v >> 17) & NMASK);
      eidr[it] = (int)(v >> 34);
      ps[it] = *(const uint4*)(Pcatb + (size_t)s * 256 + ac16 * 8);
      pd[it] = *(const uint4*)(Pcatb + (size_t)d * 256 + 128 + ac16 * 8);
      int e = min(t * 64 + it * 16 + egrp, E - 1);
      at[it] = attrp[e];
    }
  };

  int t = blockIdx.x;
  if (t < tiles) {
    load_pk(t);
    issue_gather(t);
    if (t + S < tiles) load_pk(t + S);
  }
  for (; t < tiles; t += S) {
    // ---- phase A (packed fp32): V = relu(Ps + Pd' + attr@Wa)
#pragma unroll
    for (int it = 0; it < 4; it++) {
      int e = it * 16 + egrp;
      uint4 psu = ps[it], pdu = pd[it];
      float4 a4 = at[it];
      unsigned pu[4] = {psu.x, psu.y, psu.z, psu.w};
      unsigned du[4] = {pdu.x, pdu.y, pdu.z, pdu.w};
      uint4 ov;
      unsigned* op = (unsigned*)&ov;
#pragma unroll
      for (int p2 = 0; p2 < 4; p2++) {
        f32x2 f = unpk2(pu[p2]) + unpk2(du[p2]);
        f += a4.x * wa2[0][p2];
        f += a4.y * wa2[1][p2];
        f += a4.z * wa2[2][p2];
        f += a4.w * wa2[3][p2];
        f = __builtin_elementwise_max(f, (f32x2){0.f, 0.f});
        op[p2] = packrn(f);
      }
      *(uint4*)(sV + e * 136 + ac16 * 8) = ov;
      if (ac16 == 0) *(unsigned*)(sV + e * 136 + 128) = (unsigned)eidr[it];
    }
    // ---- prefetch tile t+S (overlaps barrier + phase B)
    if (t + S < tiles) {
      issue_gather(t + S);
      if (t + 2 * S < tiles) load_pk(t + 2 * S);
    }
    __syncthreads();
    // ---- phase B: MFMA from LDS
    f32x4 acc[4];
#pragma unroll
    for (int nt = 0; nt < 4; nt++) acc[nt] = (f32x4){0.f, 0.f, 0.f, 0.f};
    const u16* vp = sV + (w * 16 + c16) * 136 + quad * 8;
#pragma unroll
    for (int kt = 0; kt < 4; kt++) {
      bf16x8 av = *(const bf16x8*)(vp + kt * 32);
#pragma unroll
      for (int nt = 0; nt < 4; nt++) {
        bf16x8 bv = *(const bf16x8*)(sW2 + ((kt * 4 + nt) * 64 + l) * 8);
        acc[nt] = __builtin_amdgcn_mfma_f32_16x16x32_bf16(av, bv, acc[nt], 0, 0, 0);
      }
    }
#pragma unroll
    for (int r = 0; r < 4; r++) {
      float p = 0.0f;
#pragma unroll
      for (int nt = 0; nt < 4; nt++)
        p += fmaxf(acc[nt][r] + be2[nt], 0.0f) * w3v[nt];
      p += __shfl_xor(p, 1, 64);
      p += __shfl_xor(p, 2, 64);
      p += __shfl_xor(p, 4, 64);
      p += __shfl_xor(p, 8, 64);
      if (c16 == 0) {
        int eloc = w * 16 + quad * 4 + r;
        if (t * 64 + eloc < E) {
          unsigned eid = *(const unsigned*)(sV + eloc * 136 + 128);
          out[eid] = p + b3;
        }
      }
    }
    __syncthreads();  // protect sV before next tile's phase A writes
  }
}

extern "C" void kernel_launch(void* const* d_in, const int* in_sizes, int n_in,
                              void* d_out, int out_size, void* d_ws,
                              size_t ws_size, hipStream_t stream) {
  const float* x        = (const float*)d_in[0];
  const int*   ei       = (const int*)d_in[1];
  const float* attr     = (const float*)d_in[2];
  const float* w1_root  = (const float*)d_in[3];
  const float* w1_neigh = (const float*)d_in[4];
  const float* b1       = (const float*)d_in[5];
  const float* w2_root  = (const float*)d_in[6];
  const float* w2_neigh = (const float*)d_in[7];
  const float* b2       = (const float*)d_in[8];
  const float* w_e1     = (const float*)d_in[9];
  const float* b_e1     = (const float*)d_in[10];
  const float* w_e2     = (const float*)d_in[11];
  const float* b_e2     = (const float*)d_in[12];
  const float* w_e3     = (const float*)d_in[13];
  const float* b_e3     = (const float*)d_in[14];
  float* out = (float*)d_out;

  int N = in_sizes[0] / 6;
  int E = in_sizes[2] / 4;
  int NBLK = (N + 255) / 256;

  int* wsi = (int*)d_ws;
  int*    rowptr  = wsi;                        // [N+1]
  int*    cursor  = wsi + 100004;               // [N]
  int*    partial = wsi + 200004;               // [512]
  uint2*  csr2    = (uint2*)(wsi + 200520);     // [E] x 8B
  float*  mean1   = (float*)(wsi + 3400520);    // [N,6]
  u16*    cat2b   = (u16*)(wsi + 4000520);      // [N,256] bf16
  u16*    h2b     = (u16*)(wsi + 16800520);     // [N,128] bf16
  u16*    B2f     = (u16*)(wsi + 23200520);     // 32768
  u16*    WSDf    = (u16*)(wsi + 23216904);     // 32768
  u16*    W2f     = (u16*)(wsi + 23233288);     // 8192
  float*  pbias   = (float*)(wsi + 23237384);   // 256
  float4* attrp   = (float4*)(wsi + 23237640);  // [E] x 16B

  (void)hipMemsetAsync(cursor, 0, (size_t)N * sizeof(int), stream);

  pack_weights<<<289, 256, 0, stream>>>(w2_root, w2_neigh, w_e1, w_e2, b_e1,
                                        B2f, WSDf, W2f, pbias);

  // CSR build (by dst), attr permuted in the same pass
  hist_kernel<<<(E + 255) / 256, 256, 0, stream>>>(ei, cursor, E);
  scan_block_sums<<<NBLK, 256, 0, stream>>>(cursor, partial, N);
  scan_partials<<<1, 512, 0, stream>>>(partial, rowptr, NBLK, E, N);
  scan_final<<<NBLK, 256, 0, stream>>>(partial, cursor, rowptr, N);
  scatter_csr<<<(E + 255) / 256, 256, 0, stream>>>(ei, attr, cursor, csr2,
                                                   attrp, E);

  // layer 1
  agg1_kernel<<<(N + 3) / 4, 256, 0, stream>>>(x, rowptr, csr2, mean1, N);
  dense1_kernel<<<1024, 256, 0, stream>>>(x, mean1, w1_root, w1_neigh, b1,
                                          cat2b, N);

  // layer 2 aggregation (6-deep pipelined bf16 gather)
  agg2_kernel<<<(N + 3) / 4, 256, 0, stream>>>(cat2b, cat2b, rowptr, csr2, N);

  int gblocks = (N + 63) / 64;
  // h2 = relu([h1|mean2] @ [w2_root;w2_neigh] + b2)
  mfma_gemm<8, 8, true><<<gblocks, 256, 0, stream>>>(cat2b, 256, B2f, b2, h2b,
                                                     128, N);
  // Pcat = h2 @ [Ws|Wd] + [0|b_e1]
  mfma_gemm<4, 16, false><<<gblocks, 256, 0, stream>>>(h2b, 128, WSDf, pbias,
                                                       cat2b, 256, N);

  // pipelined fused edge MLP (4 blocks/CU x 256 CUs)
  edge_mfma_kernel<<<1024, 256, 0, stream>>>(cat2b, csr2, attrp, w_e1, W2f,
                                             b_e2, w_e3, b_e3, out, E);
}

// Round 9
// 595.857 us; speedup vs baseline: 4.2849x; 1.0137x over previous
//
#include <hip/hip_runtime.h>
#include <hip/hip_bf16.h>
#include <stdint.h>

// ---------------------------------------------------------------------------
// UVSeamGNN R7b: R7 with workspace-layout fix (h2b needs 6.4M words; packed
// weights moved past 28,000,520 — R7 had B2f inside h2b's span => GEMM-1
// clobbered the weights). 16B packed edge record (src|dst|eid + attr bf16x4);
// src-only u32 array for agg kernels; GEMM M-tile 128 with 512 thr; agg2
// 8-deep prefetch.
// Workspace (4B words), N=100000, E=1600000:
//   rowptr @0        [N+1]
//   cursor @100004   [N]
//   partial@200004   [512]
//   src4   @200516   [E]      (src per CSR slot, for agg kernels)
//   rec    @1800520  [E*4]    (uint4: src|dstlo<<17, dsthi|eid<<2, attr01, attr23)
//   mean1  @8200520  [N*6]
//   cat2b  @8800520  [N*256]b (cols 0..127: h1/Ps; 128..255: mean2/Pd+b1)
//   h2b    @21600520 [N*128]b (6.4M words -> ends 28000520)
//   B2f    @28000520 [32768]u16   WSDf @28016904 [32768]u16
//   W2f    @28033288 [8192]u16    pbias@28037384 [256]f32
// total ~112.2 MB
// ---------------------------------------------------------------------------

typedef unsigned short u16;
typedef short bf16x8 __attribute__((ext_vector_type(8)));
typedef float f32x4 __attribute__((ext_vector_type(4)));
typedef float f32x2 __attribute__((ext_vector_type(2)));

#define NMASK 0x1FFFF

__device__ __forceinline__ u16 f2b(float f) {
  unsigned u = __builtin_bit_cast(unsigned, f);
  u = u + 0x7fffu + ((u >> 16) & 1u);
  return (u16)(u >> 16);
}
__device__ __forceinline__ float bflo(unsigned u) {
  return __builtin_bit_cast(float, u << 16);
}
__device__ __forceinline__ float bfhi(unsigned u) {
  return __builtin_bit_cast(float, u & 0xffff0000u);
}
__device__ __forceinline__ f32x2 unpk2(unsigned u) {
  return (f32x2){bflo(u), bfhi(u)};
}
__device__ __forceinline__ unsigned pack2bf(float a, float b) {
  unsigned ua = __builtin_bit_cast(unsigned, a);
  unsigned ub = __builtin_bit_cast(unsigned, b);
  ua = ua + 0x7fffu + ((ua >> 16) & 1u);
  ub = ub + 0x7fffu + ((ub >> 16) & 1u);
  return (ua >> 16) | (ub & 0xffff0000u);
}
__device__ __forceinline__ unsigned packrn(f32x2 f) {
  __hip_bfloat162 h = __float22bfloat162_rn(make_float2(f.x, f.y));
  unsigned r;
  __builtin_memcpy(&r, &h, 4);
  return r;
}

// ---- CSR build ----
__global__ void hist_kernel(const int* __restrict__ ei, int* __restrict__ cnt,
                            int E) {
  int e = blockIdx.x * blockDim.x + threadIdx.x;
  if (e < E) atomicAdd(&cnt[ei[E + e]], 1);
}

__global__ void scan_block_sums(const int* __restrict__ cnt,
                                int* __restrict__ partial, int N) {
  __shared__ int red[256];
  int t = threadIdx.x;
  int n = blockIdx.x * 256 + t;
  red[t] = (n < N) ? cnt[n] : 0;
  __syncthreads();
  for (int off = 128; off; off >>= 1) {
    if (t < off) red[t] += red[t + off];
    __syncthreads();
  }
  if (t == 0) partial[blockIdx.x] = red[0];
}

__global__ void scan_partials(int* __restrict__ partial,
                              int* __restrict__ rowptr, int NBLK, int E,
                              int N) {
  __shared__ int sc[512];
  int t = threadIdx.x;
  int v = (t < NBLK) ? partial[t] : 0;
  sc[t] = v;
  __syncthreads();
  for (int off = 1; off < 512; off <<= 1) {
    int a = (t >= off) ? sc[t - off] : 0;
    __syncthreads();
    sc[t] += a;
    __syncthreads();
  }
  if (t < NBLK) partial[t] = sc[t] - v;  // exclusive
  if (t == 0) rowptr[N] = E;
}

__global__ void scan_final(const int* __restrict__ partial,
                           int* __restrict__ cursor, int* __restrict__ rowptr,
                           int N) {
  __shared__ int sc[256];
  int t = threadIdx.x;
  int n = blockIdx.x * 256 + t;
  int v = (n < N) ? cursor[n] : 0;
  sc[t] = v;
  __syncthreads();
  for (int off = 1; off < 256; off <<= 1) {
    int a = (t >= off) ? sc[t - off] : 0;
    __syncthreads();
    sc[t] += a;
    __syncthreads();
  }
  int excl = partial[blockIdx.x] + sc[t] - v;
  if (n < N) {
    rowptr[n] = excl;
    cursor[n] = excl;
  }
}

// scatter packed 16B record + src-only array in one pass
__global__ void scatter_rec(const int* __restrict__ ei,
                            const float* __restrict__ attr,
                            int* __restrict__ cursor, uint4* __restrict__ rec,
                            unsigned* __restrict__ src4, int E) {
  int e = blockIdx.x * blockDim.x + threadIdx.x;
  if (e >= E) return;
  int s = ei[e];
  int d = ei[E + e];
  float4 a4 = *(const float4*)(attr + (size_t)e * 4);
  int pos = atomicAdd(&cursor[d], 1);
  uint4 r;
  r.x = (unsigned)s | ((unsigned)(d & 0x7FFF) << 17);
  r.y = ((unsigned)d >> 15) | ((unsigned)e << 2);
  r.z = pack2bf(a4.x, a4.y);
  r.w = pack2bf(a4.z, a4.w);
  rec[pos] = r;
  src4[pos] = (unsigned)s;
}

// ---- pack weights into bf16 MFMA B-fragment layouts ----
__global__ void pack_weights(const float* __restrict__ w2_root,
                             const float* __restrict__ w2_neigh,
                             const float* __restrict__ w_e1,
                             const float* __restrict__ w_e2,
                             const float* __restrict__ b_e1,
                             u16* __restrict__ B2f, u16* __restrict__ WSDf,
                             u16* __restrict__ W2f, float* __restrict__ pbias) {
  int t = blockIdx.x * 256 + threadIdx.x;
  if (t < 32768) {  // B2f: KT=8, NT=8 over [w2_root; w2_neigh] (K=256, N=128)
    int j = t & 7, lane = (t >> 3) & 63, nt = (t >> 9) & 7, kt = t >> 12;
    int k = kt * 32 + (lane >> 4) * 8 + j;
    int n = nt * 16 + (lane & 15);
    float v = (k < 128) ? w2_root[k * 128 + n] : w2_neigh[(k - 128) * 128 + n];
    B2f[t] = f2b(v);
  } else if (t < 65536) {  // WSDf: KT=4, NT=16 over [Ws | Wd] (K=128, N=256)
    int t2 = t - 32768;
    int j = t2 & 7, lane = (t2 >> 3) & 63, nt = (t2 >> 9) & 15, kt = t2 >> 13;
    int k = kt * 32 + (lane >> 4) * 8 + j;
    int n = nt * 16 + (lane & 15);
    float v = (n < 128) ? w_e1[k * 128 + n] : w_e1[(128 + k) * 128 + (n - 128)];
    WSDf[t2] = f2b(v);
  } else if (t < 73728) {  // W2f: KT=4, NT=4 over w_e2 (K=128, N=64)
    int t2 = t - 65536;
    int j = t2 & 7, lane = (t2 >> 3) & 63, nt = (t2 >> 9) & 3, kt = t2 >> 11;
    int k = kt * 32 + (lane >> 4) * 8 + j;
    int n = nt * 16 + (lane & 15);
    W2f[t2] = f2b(w_e2[k * 64 + n]);
  } else if (t < 73984) {  // pbias
    int n = t - 73728;
    pbias[n] = (n < 128) ? 0.0f : b_e1[n - 128];
  }
}

// ---- layer-1 mean aggregation: wave/node, 8 rows x 8 lanes, 4-deep ----
__global__ __launch_bounds__(256) void agg1_kernel(
    const float* __restrict__ x, const int* __restrict__ rowptr,
    const unsigned* __restrict__ src4, float* __restrict__ mean1, int N) {
  int n = blockIdx.x * 4 + (threadIdx.x >> 6);
  if (n >= N) return;
  int lane = threadIdx.x & 63;
  int g = lane >> 3;  // row group 0..7
  int c = lane & 7;   // col 0..7 (0..5 valid)
  int beg = rowptr[n], end = rowptr[n + 1];
  float a = 0.0f;
  if (c < 6) {
    int idx[4];
#pragma unroll
    for (int j = 0; j < 4; j++) {
      int ii = beg + g + j * 8;
      idx[j] = (ii < end) ? (int)src4[ii] : -1;
    }
    float v[4];
#pragma unroll
    for (int j = 0; j < 4; j++)
      v[j] = x[(size_t)(idx[j] < 0 ? 0 : idx[j]) * 6 + c];
#pragma unroll
    for (int j = 0; j < 4; j++)
      if (idx[j] >= 0) a += v[j];
    for (int ii = beg + g + 32; ii < end; ii += 8) {
      a += x[(size_t)src4[ii] * 6 + c];
    }
  }
  a += __shfl_xor(a, 8, 64);
  a += __shfl_xor(a, 16, 64);
  a += __shfl_xor(a, 32, 64);
  if (g == 0 && c < 6)
    mean1[(size_t)n * 6 + c] = a / (float)max(end - beg, 1);
}

// ---- dense layer 1 -> h1 bf16 into cat2b cols 0..127, LDS-staged ----
__global__ __launch_bounds__(256) void dense1_kernel(
    const float* __restrict__ x, const float* __restrict__ mean1,
    const float* __restrict__ w_root, const float* __restrict__ w_neigh,
    const float* __restrict__ b, u16* __restrict__ cat2b, int N) {
  __shared__ float sxm[384];  // [0:192) x for 32 nodes, [192:384) mean1
  int t = threadIdx.x;
  int col = t & 127;
  int half = t >> 7;
  float wr[6], wn[6];
#pragma unroll
  for (int j = 0; j < 6; j++) {
    wr[j] = w_root[j * 128 + col];
    wn[j] = w_neigh[j * 128 + col];
  }
  float bb = b[col];
  for (int base = blockIdx.x * 32; base < N; base += gridDim.x * 32) {
    int cnt = min(32, N - base) * 6;
    __syncthreads();
    for (int i = t; i < 384; i += 256) {
      if (i < 192)
        sxm[i] = (i < cnt) ? x[(size_t)base * 6 + i] : 0.0f;
      else
        sxm[i] = (i - 192 < cnt) ? mean1[(size_t)base * 6 + (i - 192)] : 0.0f;
    }
    __syncthreads();
#pragma unroll
    for (int sub = 0; sub < 16; sub++) {
      int nl = sub * 2 + half;
      int n = base + nl;
      if (n < N) {
        float s = bb;
#pragma unroll
        for (int j = 0; j < 6; j++)
          s += sxm[nl * 6 + j] * wr[j] + sxm[192 + nl * 6 + j] * wn[j];
        cat2b[(size_t)n * 256 + col] = f2b(fmaxf(s, 0.0f));
      }
    }
  }
}

// ---- layer-2 mean aggregation: wave/node, 4x16 lanes, 8-deep prefetch ----
__global__ __launch_bounds__(256) void agg2_kernel(
    const u16* __restrict__ cat2b, u16* __restrict__ cat2w,
    const int* __restrict__ rowptr, const unsigned* __restrict__ src4, int N) {
  int n = blockIdx.x * 4 + (threadIdx.x >> 6);
  if (n >= N) return;
  int lane = threadIdx.x & 63;
  int g = lane >> 4;  // row group 0..3
  int c = lane & 15;  // col chunk (8 bf16)
  int beg = rowptr[n], end = rowptr[n + 1];
  f32x2 acc2[4];
#pragma unroll
  for (int j = 0; j < 4; j++) acc2[j] = (f32x2){0.f, 0.f};

  const int DEPTH = 8;
  int idx[DEPTH];
#pragma unroll
  for (int j = 0; j < DEPTH; j++) {
    int ii = beg + g + j * 4;
    idx[j] = (ii < end) ? (int)src4[ii] : -1;
  }
  uint4 u[DEPTH];
#pragma unroll
  for (int j = 0; j < DEPTH; j++) {
    int s = idx[j] < 0 ? 0 : idx[j];
    u[j] = *(const uint4*)(cat2b + (size_t)s * 256 + c * 8);
  }
#pragma unroll
  for (int j = 0; j < DEPTH; j++) {
    if (idx[j] >= 0) {
      acc2[0] += unpk2(u[j].x);
      acc2[1] += unpk2(u[j].y);
      acc2[2] += unpk2(u[j].z);
      acc2[3] += unpk2(u[j].w);
    }
  }
  for (int ii = beg + g + DEPTH * 4; ii < end; ii += 4) {
    uint4 uu = *(const uint4*)(cat2b + (size_t)src4[ii] * 256 + c * 8);
    acc2[0] += unpk2(uu.x);
    acc2[1] += unpk2(uu.y);
    acc2[2] += unpk2(uu.z);
    acc2[3] += unpk2(uu.w);
  }
#pragma unroll
  for (int j = 0; j < 4; j++) {
    acc2[j].x += __shfl_xor(acc2[j].x, 16, 64);
    acc2[j].y += __shfl_xor(acc2[j].y, 16, 64);
    acc2[j].x += __shfl_xor(acc2[j].x, 32, 64);
    acc2[j].y += __shfl_xor(acc2[j].y, 32, 64);
  }
  if (g == 0) {
    float inv = 1.0f / (float)max(end - beg, 1);
    uint4 ov;
    ov.x = packrn(acc2[0] * inv);
    ov.y = packrn(acc2[1] * inv);
    ov.z = packrn(acc2[2] * inv);
    ov.w = packrn(acc2[3] * inv);
    *(uint4*)(cat2w + (size_t)n * 256 + 128 + c * 8) = ov;
  }
}

// ---- bf16 MFMA GEMM: 512 thr, 8 waves, M-tile 128 ----
template <int KT, int NT, bool RELU>
__global__ __launch_bounds__(512) void mfma_gemm(
    const u16* __restrict__ A, int lda, const u16* __restrict__ Bf,
    const float* __restrict__ bias, u16* __restrict__ C, int ldc, int M) {
  __shared__ u16 sB[KT * NT * 512];
  int tid = threadIdx.x;
  for (int i = tid; i < KT * NT * 64; i += 512)
    ((uint4*)sB)[i] = ((const uint4*)Bf)[i];
  int w = tid >> 6, l = tid & 63;
  int quad = l >> 4, col16 = l & 15;
  int rowA = blockIdx.x * 128 + w * 16 + col16;
  bool rv = rowA < M;
  const u16* ap = A + (size_t)rowA * lda + quad * 8;
  f32x4 acc[NT];
#pragma unroll
  for (int nt = 0; nt < NT; nt++) acc[nt] = (f32x4){0.f, 0.f, 0.f, 0.f};
  __syncthreads();
#pragma unroll
  for (int kt = 0; kt < KT; kt++) {
    bf16x8 av = {};
    if (rv) av = *(const bf16x8*)(ap + kt * 32);
#pragma unroll
    for (int nt = 0; nt < NT; nt++) {
      bf16x8 bv = *(const bf16x8*)(sB + ((kt * NT + nt) * 64 + l) * 8);
      acc[nt] = __builtin_amdgcn_mfma_f32_16x16x32_bf16(av, bv, acc[nt], 0, 0, 0);
    }
  }
  int rowbase = blockIdx.x * 128 + w * 16 + quad * 4;
#pragma unroll
  for (int r = 0; r < 4; r++) {
    int row = rowbase + r;
    if (row < M) {
#pragma unroll
      for (int nt = 0; nt < NT; nt++) {
        float v = acc[nt][r] + bias[nt * 16 + col16];
        if (RELU) v = fmaxf(v, 0.0f);
        C[(size_t)row * ldc + nt * 16 + col16] = f2b(v);
      }
    }
  }
}

// ---- pipelined edge MLP, packed record, single-buffer LDS ----
__global__ __launch_bounds__(256) void edge_mfma_kernel(
    const u16* __restrict__ Pcatb, const uint4* __restrict__ rec,
    const u16* __restrict__ W2f, const float* __restrict__ b_e2,
    const float* __restrict__ w_e3, const float* __restrict__ b_e3,
    const float* __restrict__ w_e1, float* __restrict__ out, int E) {
  __shared__ u16 sV[64 * 136];  // cols 0..127 = V, u16 slot 128.. = eid
  __shared__ u16 sW2[8192];

  int tid = threadIdx.x;
  int w = tid >> 6, l = tid & 63, quad = l >> 4, c16 = l & 15;
  int egrp = tid >> 4, ac16 = tid & 15;

  for (int i = tid; i < 1024; i += 256)
    ((uint4*)sW2)[i] = ((const uint4*)W2f)[i];

  // wa2[j][p2]: rows j=0..3 of Wa, column pair p2 for this thread's 8 cols
  f32x2 wa2[4][4];
#pragma unroll
  for (int j = 0; j < 4; j++) {
    float4 w0 = *(const float4*)(w_e1 + (256 + j) * 128 + ac16 * 8);
    float4 w1 = *(const float4*)(w_e1 + (256 + j) * 128 + ac16 * 8 + 4);
    wa2[j][0] = (f32x2){w0.x, w0.y};
    wa2[j][1] = (f32x2){w0.z, w0.w};
    wa2[j][2] = (f32x2){w1.x, w1.y};
    wa2[j][3] = (f32x2){w1.z, w1.w};
  }
  float w3v[4], be2[4];
#pragma unroll
  for (int nt = 0; nt < 4; nt++) {
    w3v[nt] = w_e3[nt * 16 + c16];
    be2[nt] = b_e2[nt * 16 + c16];
  }
  float b3 = b_e3[0];

  int tiles = (E + 63) >> 6;
  int S = gridDim.x;

  uint4 rc[4];
  uint4 ps[4], pd[4];
  int eidr[4];

  auto load_rec = [&](int t) {
#pragma unroll
    for (int it = 0; it < 4; it++) {
      int e = min(t * 64 + it * 16 + egrp, E - 1);
      rc[it] = rec[e];
    }
  };
  auto issue_gather = [&]() {
#pragma unroll
    for (int it = 0; it < 4; it++) {
      int s = (int)(rc[it].x & NMASK);
      int d = (int)(((rc[it].x >> 17) | (rc[it].y << 15)) & NMASK);
      eidr[it] = (int)(rc[it].y >> 2);
      ps[it] = *(const uint4*)(Pcatb + (size_t)s * 256 + ac16 * 8);
      pd[it] = *(const uint4*)(Pcatb + (size_t)d * 256 + 128 + ac16 * 8);
    }
  };

  int t = blockIdx.x;
  uint4 rcn[4];
  if (t < tiles) {
    load_rec(t);
    issue_gather();
    if (t + S < tiles) {
#pragma unroll
      for (int it = 0; it < 4; it++) {
        int e = min((t + S) * 64 + it * 16 + egrp, E - 1);
        rcn[it] = rec[e];
      }
    }
  }
  for (; t < tiles; t += S) {
    // ---- phase A (packed fp32): V = relu(Ps + Pd' + attr@Wa)
#pragma unroll
    for (int it = 0; it < 4; it++) {
      int e = it * 16 + egrp;
      uint4 psu = ps[it], pdu = pd[it];
      f32x2 a01 = unpk2(rc[it].z);
      f32x2 a23 = unpk2(rc[it].w);
      unsigned pu[4] = {psu.x, psu.y, psu.z, psu.w};
      unsigned du[4] = {pdu.x, pdu.y, pdu.z, pdu.w};
      uint4 ov;
      unsigned* op = (unsigned*)&ov;
#pragma unroll
      for (int p2 = 0; p2 < 4; p2++) {
        f32x2 f = unpk2(pu[p2]) + unpk2(du[p2]);
        f += a01.x * wa2[0][p2];
        f += a01.y * wa2[1][p2];
        f += a23.x * wa2[2][p2];
        f += a23.y * wa2[3][p2];
        f = __builtin_elementwise_max(f, (f32x2){0.f, 0.f});
        op[p2] = packrn(f);
      }
      *(uint4*)(sV + e * 136 + ac16 * 8) = ov;
      if (ac16 == 0) *(unsigned*)(sV + e * 136 + 128) = (unsigned)eidr[it];
    }
    // ---- rotate prefetch: rc <- rcn, gather t+S, load rec t+2S
    if (t + S < tiles) {
#pragma unroll
      for (int it = 0; it < 4; it++) rc[it] = rcn[it];
      issue_gather();
      if (t + 2 * S < tiles) {
#pragma unroll
        for (int it = 0; it < 4; it++) {
          int e = min((t + 2 * S) * 64 + it * 16 + egrp, E - 1);
          rcn[it] = rec[e];
        }
      }
    }
    __syncthreads();
    // ---- phase B: MFMA from LDS
    f32x4 acc[4];
#pragma unroll
    for (int nt = 0; nt < 4; nt++) acc[nt] = (f32x4){0.f, 0.f, 0.f, 0.f};
    const u16* vp = sV + (w * 16 + c16) * 136 + quad * 8;
#pragma unroll
    for (int kt = 0; kt < 4; kt++) {
      bf16x8 av = *(const bf16x8*)(vp + kt * 32);
#pragma unroll
      for (int nt = 0; nt < 4; nt++) {
        bf16x8 bv = *(const bf16x8*)(sW2 + ((kt * 4 + nt) * 64 + l) * 8);
        acc[nt] = __builtin_amdgcn_mfma_f32_16x16x32_bf16(av, bv, acc[nt], 0, 0, 0);
      }
    }
#pragma unroll
    for (int r = 0; r < 4; r++) {
      float p = 0.0f;
#pragma unroll
      for (int nt = 0; nt < 4; nt++)
        p += fmaxf(acc[nt][r] + be2[nt], 0.0f) * w3v[nt];
      p += __shfl_xor(p, 1, 64);
      p += __shfl_xor(p, 2, 64);
      p += __shfl_xor(p, 4, 64);
      p += __shfl_xor(p, 8, 64);
      if (c16 == 0) {
        int eloc = w * 16 + quad * 4 + r;
        if (t * 64 + eloc < E) {
          unsigned eid = *(const unsigned*)(sV + eloc * 136 + 128);
          out[eid] = p + b3;
        }
      }
    }
    __syncthreads();  // protect sV before next tile's phase A writes
  }
}

extern "C" void kernel_launch(void* const* d_in, const int* in_sizes, int n_in,
                              void* d_out, int out_size, void* d_ws,
                              size_t ws_size, hipStream_t stream) {
  const float* x        = (const float*)d_in[0];
  const int*   ei       = (const int*)d_in[1];
  const float* attr     = (const float*)d_in[2];
  const float* w1_root  = (const float*)d_in[3];
  const float* w1_neigh = (const float*)d_in[4];
  const float* b1       = (const float*)d_in[5];
  const float* w2_root  = (const float*)d_in[6];
  const float* w2_neigh = (const float*)d_in[7];
  const float* b2       = (const float*)d_in[8];
  const float* w_e1     = (const float*)d_in[9];
  const float* b_e1     = (const float*)d_in[10];
  const float* w_e2     = (const float*)d_in[11];
  const float* b_e2     = (const float*)d_in[12];
  const float* w_e3     = (const float*)d_in[13];
  const float* b_e3     = (const float*)d_in[14];
  float* out = (float*)d_out;

  int N = in_sizes[0] / 6;
  int E = in_sizes[2] / 4;
  int NBLK = (N + 255) / 256;

  int* wsi = (int*)d_ws;
  int*      rowptr  = wsi;                         // [N+1]
  int*      cursor  = wsi + 100004;                // [N]
  int*      partial = wsi + 200004;                // [512]
  unsigned* src4    = (unsigned*)(wsi + 200516);   // [E]
  uint4*    rec     = (uint4*)(wsi + 1800520);     // [E] x 16B
  float*    mean1   = (float*)(wsi + 8200520);     // [N,6]
  u16*      cat2b   = (u16*)(wsi + 8800520);       // [N,256] bf16
  u16*      h2b     = (u16*)(wsi + 21600520);      // [N,128] bf16 (6.4M words)
  u16*      B2f     = (u16*)(wsi + 28000520);      // 32768 u16
  u16*      WSDf    = (u16*)(wsi + 28016904);      // 32768 u16
  u16*      W2f     = (u16*)(wsi + 28033288);      // 8192 u16
  float*    pbias   = (float*)(wsi + 28037384);    // 256 f32

  (void)hipMemsetAsync(cursor, 0, (size_t)N * sizeof(int), stream);

  pack_weights<<<289, 256, 0, stream>>>(w2_root, w2_neigh, w_e1, w_e2, b_e1,
                                        B2f, WSDf, W2f, pbias);

  // CSR build (by dst), attr packed into 16B records
  hist_kernel<<<(E + 255) / 256, 256, 0, stream>>>(ei, cursor, E);
  scan_block_sums<<<NBLK, 256, 0, stream>>>(cursor, partial, N);
  scan_partials<<<1, 512, 0, stream>>>(partial, rowptr, NBLK, E, N);
  scan_final<<<NBLK, 256, 0, stream>>>(partial, cursor, rowptr, N);
  scatter_rec<<<(E + 255) / 256, 256, 0, stream>>>(ei, attr, cursor, rec,
                                                   src4, E);

  // layer 1
  agg1_kernel<<<(N + 3) / 4, 256, 0, stream>>>(x, rowptr, src4, mean1, N);
  dense1_kernel<<<1024, 256, 0, stream>>>(x, mean1, w1_root, w1_neigh, b1,
                                          cat2b, N);

  // layer 2 aggregation (8-deep pipelined bf16 gather)
  agg2_kernel<<<(N + 3) / 4, 256, 0, stream>>>(cat2b, cat2b, rowptr, src4, N);

  int gblocks = (N + 127) / 128;
  // h2 = relu([h1|mean2] @ [w2_root;w2_neigh] + b2)
  mfma_gemm<8, 8, true><<<gblocks, 512, 0, stream>>>(cat2b, 256, B2f, b2, h2b,
                                                     128, N);
  // Pcat = h2 @ [Ws|Wd] + [0|b_e1]
  mfma_gemm<4, 16, false><<<gblocks, 512, 0, stream>>>(h2b, 128, WSDf, pbias,
                                                       cat2b, 256, N);

  // pipelined fused edge MLP
  edge_mfma_kernel<<<1024, 256, 0, stream>>>(cat2b, rec, W2f, b_e2, w_e3,
                                             b_e3, w_e1, out, E);
}